// Round 5
// baseline (321.803 us; speedup 1.0000x reference)
//
#include <hip/hip_runtime.h>

typedef __bf16 bf16;
typedef bf16 bf16x4 __attribute__((ext_vector_type(4)));
typedef bf16 bf16x8 __attribute__((ext_vector_type(8)));
typedef float f32x4 __attribute__((ext_vector_type(4)));

#define B_ 2
#define S_ 4096
#define D_ 1024

__device__ __forceinline__ void gload_lds16(const void* g, void* l) {
  __builtin_amdgcn_global_load_lds((const __attribute__((address_space(1))) void*)g,
                                   (__attribute__((address_space(3))) void*)l, 16, 0, 0);
}

// ---------------- convert: f32 -> bf16 elementwise ----------------
__global__ __launch_bounds__(256) void convert_kernel(const float* __restrict__ in,
                                                      bf16* __restrict__ out, int n4) {
  for (int i = blockIdx.x * 256 + threadIdx.x; i < n4; i += gridDim.x * 256) {
    const float4 v = ((const float4*)in)[i];
    bf16x4 o = {(bf16)v.x, (bf16)v.y, (bf16)v.z, (bf16)v.w};
    *(bf16x4*)&out[i * 4] = o;
  }
}

// ---------------- transpose+convert: in f32 [K][N] -> out bf16 [N][K] ----------------
__global__ void transpose_convert(const float* __restrict__ in, bf16* __restrict__ out,
                                  int K, int N) {
  __shared__ float tile[32][33];
  const int nb = blockIdx.x * 32;
  const int kb = blockIdx.y * 32;
  const int tx = threadIdx.x, ty = threadIdx.y;
#pragma unroll
  for (int j = 0; j < 4; j++)
    tile[ty + j * 8][tx] = in[(size_t)(kb + ty + j * 8) * N + nb + tx];
  __syncthreads();
#pragma unroll
  for (int j = 0; j < 4; j++)
    out[(size_t)(nb + ty + j * 8) * K + kb + tx] = (bf16)tile[tx][ty + j * 8];
}

// ---------------- 128-tile GEMM (kept for small shapes) ----------------
template <typename OutT>
__global__ __launch_bounds__(256) void gemm_bias_kernel(
    const bf16* __restrict__ A, const bf16* __restrict__ Bt,
    const float* __restrict__ bias, OutT* __restrict__ C,
    int M, int N, int K)
{
  __shared__ __align__(16) bf16 Al[128 * 32];
  __shared__ __align__(16) bf16 Bl[128 * 32];
  const int m0 = blockIdx.x * 128;
  const int n0 = blockIdx.y * 128;
  const int t = threadIdx.x;
  const int lane = t & 63;
  const int wave = t >> 6;
  const int wr = (wave >> 1) * 64;
  const int wc = (wave & 1) * 64;
  const int r16 = lane & 15;
  const int kg = lane >> 4;

  f32x4 acc[4][4];
#pragma unroll
  for (int i = 0; i < 4; i++)
#pragma unroll
    for (int j = 0; j < 4; j++) {
      f32x4 z = {0.f, 0.f, 0.f, 0.f};
      acc[i][j] = z;
    }

  for (int k0 = 0; k0 < K; k0 += 32) {
    __syncthreads();
#pragma unroll
    for (int i = 0; i < 2; i++) {
      const int o = i * 4096 + wave * 1024 + lane * 16;
      const int r = o >> 6;
      const int cb = o & 63;
      gload_lds16((const char*)(A + (size_t)(m0 + r) * K + k0) + cb,
                  (char*)Al + i * 4096 + wave * 1024);
      gload_lds16((const char*)(Bt + (size_t)(n0 + r) * K + k0) + cb,
                  (char*)Bl + i * 4096 + wave * 1024);
    }
    __syncthreads();
    bf16x8 a[4], b[4];
#pragma unroll
    for (int i = 0; i < 4; i++)
      a[i] = *(const bf16x8*)&Al[(wr + i * 16 + r16) * 32 + kg * 8];
#pragma unroll
    for (int i = 0; i < 4; i++)
      b[i] = *(const bf16x8*)&Bl[(wc + i * 16 + r16) * 32 + kg * 8];
#pragma unroll
    for (int i = 0; i < 4; i++)
#pragma unroll
      for (int j = 0; j < 4; j++)
        acc[i][j] = __builtin_amdgcn_mfma_f32_16x16x32_bf16(a[i], b[j], acc[i][j], 0, 0, 0);
  }

  float bs[4];
#pragma unroll
  for (int j = 0; j < 4; j++) bs[j] = bias[n0 + wc + j * 16 + r16];
#pragma unroll
  for (int i = 0; i < 4; i++)
#pragma unroll
    for (int j = 0; j < 4; j++)
#pragma unroll
      for (int r = 0; r < 4; r++) {
        const int row = m0 + wr + i * 16 + kg * 4 + r;
        const int col = n0 + wc + j * 16 + r16;
        C[(size_t)row * N + col] = (OutT)(acc[i][j][r] + bs[j]);
      }
}

// ---------------- 256x256 8-phase GEMM (T2 swizzle + T3/T4 counted vmcnt + T5) ---------
// BK=64, 512 threads (8 waves, 2M x 4N), per-wave 128x64 out, dbuf 128 KiB LDS.
// LDS rows 128B; 16B chunk c stored at c ^ (row&7) (involution; pre-swizzled global src).
template <typename OutT>
__global__ __launch_bounds__(512, 1) void gemm8_kernel(
    const bf16* __restrict__ A, const bf16* __restrict__ Bt,
    const float* __restrict__ bias, OutT* __restrict__ C,
    int M, int N, int K)
{
  __shared__ __align__(16) bf16 Al[2][256 * 64];
  __shared__ __align__(16) bf16 Bl[2][256 * 64];

  const int nbx = gridDim.x;
  const int nwg = nbx * gridDim.y;
  int bid = blockIdx.y * nbx + blockIdx.x;
  bid = (bid & 7) * (nwg >> 3) + (bid >> 3);   // XCD swizzle (nwg % 8 == 0)
  const int m0 = (bid % nbx) * 256;
  const int n0 = (bid / nbx) * 256;

  const int t = threadIdx.x;
  const int lane = t & 63;
  const int w = t >> 6;      // wave 0..7
  const int wm = w >> 2;     // 0..1 (M half)
  const int wn = w & 3;      // 0..3 (N quarter)
  const int l15 = lane & 15;
  const int kg = lane >> 4;

  // staging: round = 64 rows (8KB); thread t -> row srow, swizzled chunk
  const int srow = t >> 3;
  const int schunk = (t & 7) ^ (srow & 7);
  const bf16* Asrc = A + (size_t)(m0 + srow) * K + schunk * 8;
  const bf16* Bsrc = Bt + (size_t)(n0 + srow) * K + schunk * 8;
  const int ldsoff = w * 1024;  // wave's 1KB slice within an 8KB round

  const int NT = K >> 6;

  // fragment read offsets (bytes): row*128 + swizzled-chunk*16
  const int arow = wm * 128 + l15;
  const int brow = wn * 64 + l15;
  const int c0 = ((0 * 4 + kg) ^ (l15 & 7)) * 16;  // ksub 0
  const int c1 = ((1 * 4 + kg) ^ (l15 & 7)) * 16;  // ksub 1

  f32x4 acc[8][4];
#pragma unroll
  for (int i = 0; i < 8; i++)
#pragma unroll
    for (int j = 0; j < 4; j++) { f32x4 z = {0, 0, 0, 0}; acc[i][j] = z; }

  // prologue: stage K-tiles 0,1 fully
  for (int kt = 0; kt < 2 && kt < NT; kt++) {
#pragma unroll
    for (int rd = 0; rd < 4; rd++)
      gload_lds16(Bsrc + (size_t)(rd * 64) * K + kt * 64, (char*)&Bl[kt][0] + rd * 8192 + ldsoff);
#pragma unroll
    for (int rd = 0; rd < 4; rd++)
      gload_lds16(Asrc + (size_t)(rd * 64) * K + kt * 64, (char*)&Al[kt][0] + rd * 8192 + ldsoff);
  }
  asm volatile("s_waitcnt vmcnt(0)" ::: "memory");
  __syncthreads();

  bf16x8 af[4][2], bfr[4][2];

  for (int kt = 0; kt < NT; kt++) {
    const int cur = kt & 1;
    const bool st = (kt + 2) < NT;
    const char* Ab = (const char*)&Al[cur][0];
    const char* Bb = (const char*)&Bl[cur][0];

    // ---- P0: read A i0-3, B j0-1 ; MFMA i0-3 x j0-1
#pragma unroll
    for (int i = 0; i < 4; i++) {
      af[i][0] = *(const bf16x8*)(Ab + (arow + i * 16) * 128 + c0);
      af[i][1] = *(const bf16x8*)(Ab + (arow + i * 16) * 128 + c1);
    }
#pragma unroll
    for (int j = 0; j < 2; j++) {
      bfr[j][0] = *(const bf16x8*)(Bb + (brow + j * 16) * 128 + c0);
      bfr[j][1] = *(const bf16x8*)(Bb + (brow + j * 16) * 128 + c1);
    }
    __builtin_amdgcn_s_barrier();
    asm volatile("s_waitcnt lgkmcnt(0)" ::: "memory");
    __builtin_amdgcn_sched_barrier(0);
    __builtin_amdgcn_s_setprio(1);
#pragma unroll
    for (int i = 0; i < 4; i++)
#pragma unroll
      for (int j = 0; j < 2; j++) {
        acc[i][j] = __builtin_amdgcn_mfma_f32_16x16x32_bf16(af[i][0], bfr[j][0], acc[i][j], 0, 0, 0);
        acc[i][j] = __builtin_amdgcn_mfma_f32_16x16x32_bf16(af[i][1], bfr[j][1], acc[i][j], 0, 0, 0);
      }
    __builtin_amdgcn_s_setprio(0);
    __builtin_amdgcn_s_barrier();

    // ---- P1: read B j2-3 ; MFMA i0-3 x j2-3
#pragma unroll
    for (int j = 2; j < 4; j++) {
      bfr[j][0] = *(const bf16x8*)(Bb + (brow + j * 16) * 128 + c0);
      bfr[j][1] = *(const bf16x8*)(Bb + (brow + j * 16) * 128 + c1);
    }
    __builtin_amdgcn_s_barrier();
    asm volatile("s_waitcnt lgkmcnt(0)" ::: "memory");
    __builtin_amdgcn_sched_barrier(0);
    __builtin_amdgcn_s_setprio(1);
#pragma unroll
    for (int i = 0; i < 4; i++)
#pragma unroll
      for (int j = 2; j < 4; j++) {
        acc[i][j] = __builtin_amdgcn_mfma_f32_16x16x32_bf16(af[i][0], bfr[j][0], acc[i][j], 0, 0, 0);
        acc[i][j] = __builtin_amdgcn_mfma_f32_16x16x32_bf16(af[i][1], bfr[j][1], acc[i][j], 0, 0, 0);
      }
    __builtin_amdgcn_s_setprio(0);
    __builtin_amdgcn_s_barrier();

    // ---- P2: read A i4-7 ; stage B rounds of kt+2 (B reads done end of P1) ; MFMA i4-7 x j0-1
#pragma unroll
    for (int i = 0; i < 4; i++) {
      af[i][0] = *(const bf16x8*)(Ab + (arow + (i + 4) * 16) * 128 + c0);
      af[i][1] = *(const bf16x8*)(Ab + (arow + (i + 4) * 16) * 128 + c1);
    }
    if (st) {
#pragma unroll
      for (int rd = 0; rd < 4; rd++)
        gload_lds16(Bsrc + (size_t)(rd * 64) * K + (kt + 2) * 64, (char*)&Bl[cur][0] + rd * 8192 + ldsoff);
    }
    __builtin_amdgcn_s_barrier();
    asm volatile("s_waitcnt lgkmcnt(0)" ::: "memory");
    __builtin_amdgcn_sched_barrier(0);
    __builtin_amdgcn_s_setprio(1);
#pragma unroll
    for (int i = 0; i < 4; i++)
#pragma unroll
      for (int j = 0; j < 2; j++) {
        acc[i + 4][j] = __builtin_amdgcn_mfma_f32_16x16x32_bf16(af[i][0], bfr[j][0], acc[i + 4][j], 0, 0, 0);
        acc[i + 4][j] = __builtin_amdgcn_mfma_f32_16x16x32_bf16(af[i][1], bfr[j][1], acc[i + 4][j], 0, 0, 0);
      }
    __builtin_amdgcn_s_setprio(0);
    __builtin_amdgcn_s_barrier();

    // ---- P3: stage A rounds of kt+2 (A reads done end of P2) ; MFMA i4-7 x j2-3 ; counted vmcnt
    if (st) {
#pragma unroll
      for (int rd = 0; rd < 4; rd++)
        gload_lds16(Asrc + (size_t)(rd * 64) * K + (kt + 2) * 64, (char*)&Al[cur][0] + rd * 8192 + ldsoff);
    }
    __builtin_amdgcn_s_setprio(1);
#pragma unroll
    for (int i = 0; i < 4; i++)
#pragma unroll
      for (int j = 2; j < 4; j++) {
        acc[i + 4][j] = __builtin_amdgcn_mfma_f32_16x16x32_bf16(af[i][0], bfr[j][0], acc[i + 4][j], 0, 0, 0);
        acc[i + 4][j] = __builtin_amdgcn_mfma_f32_16x16x32_bf16(af[i][1], bfr[j][1], acc[i + 4][j], 0, 0, 0);
      }
    __builtin_amdgcn_s_setprio(0);
    if (st) asm volatile("s_waitcnt vmcnt(8)" ::: "memory");
    else    asm volatile("s_waitcnt vmcnt(0)" ::: "memory");
    __builtin_amdgcn_s_barrier();
  }

  float bs[4];
#pragma unroll
  for (int j = 0; j < 4; j++) bs[j] = bias[n0 + wn * 64 + j * 16 + l15];
#pragma unroll
  for (int i = 0; i < 8; i++)
#pragma unroll
    for (int j = 0; j < 4; j++)
#pragma unroll
      for (int rr = 0; rr < 4; rr++) {
        const int row = m0 + wm * 128 + i * 16 + kg * 4 + rr;
        const int col = n0 + wn * 64 + j * 16 + l15;
        C[(size_t)row * N + col] = (OutT)(acc[i][j][rr] + bs[j]);
      }
}

// ---------------- pooling ----------------
__global__ __launch_bounds__(256) void pool_kernel(const float* __restrict__ x,
                                                   bf16* __restrict__ pooled) {
  const int blk = blockIdx.x;
  const int b = blk >> 6, lt = blk & 63;
  const int t = threadIdx.x;
  for (int d = t; d < D_; d += 256) {
    const float* p = x + ((size_t)b * S_ + lt * 64) * D_ + d;
    float sum = 0.f;
#pragma unroll
    for (int c = 0; c < 64; c++) sum += p[(size_t)c * D_];
    pooled[(size_t)blk * D_ + d] = (bf16)(sum * 0.015625f);
  }
}

// ---------------- latent attention ----------------
__global__ __launch_bounds__(256) void latent_attn_kernel(
    const bf16* __restrict__ rqb, const bf16* __restrict__ rkvb,
    bf16* __restrict__ latout)
{
  __shared__ float rq_s[256];
  __shared__ float attn_s[4][64];
  const int blk = blockIdx.x;
  const int b = blk >> 12, s = blk & 4095;
  const int t = threadIdx.x;
  const int h = t >> 6, l = t & 63;
  const int cid = s >> 6;
  rq_s[t] = (float)rqb[((size_t)b * S_ + s) * 256 + t];
  __syncthreads();
  float val = -1e30f;
  if (l < cid) {
    const bf16* kr = rkvb + (size_t)(b * 64 + l) * 512 + h * 64;
    float sum = 0.f;
#pragma unroll
    for (int c = 0; c < 8; c++) {
      bf16x8 kv = *(const bf16x8*)(kr + c * 8);
#pragma unroll
      for (int j = 0; j < 8; j++) sum += rq_s[h * 64 + c * 8 + j] * (float)kv[j];
    }
    val = sum * 0.125f;
  }
  float mx = val;
#pragma unroll
  for (int off = 32; off; off >>= 1) mx = fmaxf(mx, __shfl_xor(mx, off));
  const float p = (l < cid) ? __expf(val - mx) : 0.f;
  float sm = p;
#pragma unroll
  for (int off = 32; off; off >>= 1) sm += __shfl_xor(sm, off);
  attn_s[h][l] = (sm > 0.f) ? p / sm : 0.f;
  __syncthreads();
  float o = 0.f;
  const bf16* vb = rkvb + (size_t)b * 64 * 512 + 256 + h * 64 + l;
  for (int lat = 0; lat < cid; lat++) o += attn_s[h][lat] * (float)vb[(size_t)lat * 512];
  latout[((size_t)b * S_ + s) * 256 + h * 64 + l] = (bf16)o;
}

// ---------------- local windowed attention, MFMA version ----------------
__global__ __launch_bounds__(256) void local_attn_mfma(
    const bf16* __restrict__ qkv, bf16* __restrict__ localb)
{
  __shared__ __align__(16) bf16 Kl[128 * 72];
  __shared__ __align__(16) bf16 Vt[64 * 136];
  __shared__ __align__(16) bf16 Pl[4][16 * 136];

  const int q0 = blockIdx.x * 128;
  const int h  = blockIdx.y;
  const int b  = blockIdx.z;
  const int t  = threadIdx.x;
  const int w  = t >> 6;
  const int l  = t & 63;
  const int g  = l >> 4;
  const int l15 = l & 15;

  const bf16* qbase = qkv + (size_t)b * S_ * 3072 + h * 64;
  const bf16* kbase = qbase + 1024;
  const bf16* vbase = qbase + 2048;

  bf16x8 qf[2][2];
#pragma unroll
  for (int qg = 0; qg < 2; qg++)
#pragma unroll
    for (int db = 0; db < 2; db++)
      qf[qg][db] = *(const bf16x8*)(qbase + (size_t)(q0 + w * 32 + qg * 16 + l15) * 3072 + db * 32 + g * 8);

  float m_[2][4], l_[2][4];
  f32x4 accO[2][4];
#pragma unroll
  for (int qg = 0; qg < 2; qg++) {
#pragma unroll
    for (int r = 0; r < 4; r++) { m_[qg][r] = -1e30f; l_[qg][r] = 0.f; }
#pragma unroll
    for (int dt = 0; dt < 4; dt++) { f32x4 z = {0,0,0,0}; accO[qg][dt] = z; }
  }

  const int tstart = (q0 == 0) ? 1 : 0;
  for (int tile = tstart; tile < 2; tile++) {
    const int base = q0 - 128 + tile * 128;
    __syncthreads();
#pragma unroll
    for (int i = 0; i < 4; i++) {
      const int c = i * 256 + t;
      const int k = c >> 3, dc = c & 7;
      *(bf16x8*)&Kl[k * 72 + dc * 8] = *(const bf16x8*)(kbase + (size_t)(base + k) * 3072 + dc * 8);
    }
    {
      const int k = t & 127, dh = (t >> 7) * 32;
#pragma unroll
      for (int i = 0; i < 4; i++) {
        bf16x8 v = *(const bf16x8*)(vbase + (size_t)(base + k) * 3072 + dh + i * 8);
#pragma unroll
        for (int j = 0; j < 8; j++)
          Vt[(dh + i * 8 + j) * 136 + k] = v[j];
      }
    }
    __syncthreads();

    const int kt_lo = (tile == 0) ? 2 * w : 0;
    const int kt_hi = (tile == 0) ? 8 : 2 * w + 2;
    const int nkt = kt_hi - kt_lo;

    f32x4 s[2][8];
#pragma unroll
    for (int qg = 0; qg < 2; qg++)
#pragma unroll
      for (int kk = 0; kk < 8; kk++) { f32x4 z = {0,0,0,0}; s[qg][kk] = z; }

#pragma unroll
    for (int kk = 0; kk < 8; kk++) {
      if (kk >= nkt) continue;
      const int kt = kt_lo + kk;
      const bf16x8 kf0 = *(const bf16x8*)&Kl[(kt * 16 + l15) * 72 + g * 8];
      const bf16x8 kf1 = *(const bf16x8*)&Kl[(kt * 16 + l15) * 72 + 32 + g * 8];
      s[0][kk] = __builtin_amdgcn_mfma_f32_16x16x32_bf16(qf[0][0], kf0, s[0][kk], 0, 0, 0);
      s[0][kk] = __builtin_amdgcn_mfma_f32_16x16x32_bf16(qf[0][1], kf1, s[0][kk], 0, 0, 0);
      s[1][kk] = __builtin_amdgcn_mfma_f32_16x16x32_bf16(qf[1][0], kf0, s[1][kk], 0, 0, 0);
      s[1][kk] = __builtin_amdgcn_mfma_f32_16x16x32_bf16(qf[1][1], kf1, s[1][kk], 0, 0, 0);
    }

#pragma unroll
    for (int qg = 0; qg < 2; qg++) {
#pragma unroll
      for (int kk = 0; kk < 8; kk++) {
        if (kk >= nkt) continue;
        const int kr = (kt_lo + kk) * 16 + l15;
#pragma unroll
        for (int r = 0; r < 4; r++) {
          const int qr = w * 32 + qg * 16 + g * 4 + r;
          const bool ok = (tile == 0) ? (kr >= qr) : (kr < qr);
          s[qg][kk][r] = ok ? s[qg][kk][r] * 0.125f : -1e9f;
        }
      }
      float corr[4];
#pragma unroll
      for (int r = 0; r < 4; r++) {
        float v = -1e30f;
#pragma unroll
        for (int kk = 0; kk < 8; kk++) { if (kk >= nkt) continue; v = fmaxf(v, s[qg][kk][r]); }
        v = fmaxf(v, __shfl_xor(v, 1));
        v = fmaxf(v, __shfl_xor(v, 2));
        v = fmaxf(v, __shfl_xor(v, 4));
        v = fmaxf(v, __shfl_xor(v, 8));
        const float mn = fmaxf(m_[qg][r], v);
        corr[r] = __expf(m_[qg][r] - mn);
        m_[qg][r] = mn;
      }
      float rs[4] = {0.f, 0.f, 0.f, 0.f};
#pragma unroll
      for (int kk = 0; kk < 8; kk++) {
        if (kk >= nkt) continue;
        const int kt = kt_lo + kk;
#pragma unroll
        for (int r = 0; r < 4; r++) {
          const float sv = s[qg][kk][r];
          const float p = (sv > -5e8f) ? __expf(sv - m_[qg][r]) : 0.f;
          rs[r] += p;
          Pl[w][(g * 4 + r) * 136 + kt * 16 + l15] = (bf16)p;
        }
      }
#pragma unroll
      for (int r = 0; r < 4; r++) {
        float v = rs[r];
        v += __shfl_xor(v, 1); v += __shfl_xor(v, 2);
        v += __shfl_xor(v, 4); v += __shfl_xor(v, 8);
        l_[qg][r] = l_[qg][r] * corr[r] + v;
#pragma unroll
        for (int dt = 0; dt < 4; dt++) accO[qg][dt][r] *= corr[r];
      }
      asm volatile("s_waitcnt lgkmcnt(0)" ::: "memory");
      __builtin_amdgcn_sched_barrier(0);
      const int kc_lo = (tile == 0) ? w : 0;
      const int kc_hi = (tile == 0) ? 4 : w + 1;
#pragma unroll
      for (int kc = 0; kc < 4; kc++) {
        if (kc < kc_lo || kc >= kc_hi) continue;
        const bf16x8 pa = *(const bf16x8*)&Pl[w][l15 * 136 + kc * 32 + g * 8];
#pragma unroll
        for (int dt = 0; dt < 4; dt++) {
          const bf16x8 vf = *(const bf16x8*)&Vt[(dt * 16 + l15) * 136 + kc * 32 + g * 8];
          accO[qg][dt] = __builtin_amdgcn_mfma_f32_16x16x32_bf16(pa, vf, accO[qg][dt], 0, 0, 0);
        }
      }
    }
  }

  bf16* outp = localb + ((size_t)b * S_ + q0 + w * 32) * 1024 + h * 64;
#pragma unroll
  for (int qg = 0; qg < 2; qg++)
#pragma unroll
    for (int r = 0; r < 4; r++) {
      const float inv = (l_[qg][r] > 0.f) ? 1.f / l_[qg][r] : 0.f;
#pragma unroll
      for (int dt = 0; dt < 4; dt++)
        outp[(size_t)(qg * 16 + g * 4 + r) * 1024 + dt * 16 + l15] = (bf16)(accO[qg][dt][r] * inv);
    }
}

// ---------------- gate + mix ----------------
__global__ __launch_bounds__(1024) void gate_mix_kernel(
    const bf16* __restrict__ localb, const bf16* __restrict__ remote,
    const float* __restrict__ glw, const float* __restrict__ grw,
    bf16* __restrict__ mixed)
{
  const int blk = blockIdx.x;
  const int b = blk >> 12, s = blk & 4095;
  const int t = threadIdx.x;
  const int d = t & 63;
  const size_t idx = ((size_t)b * S_ + s) * 1024 + t;
  const float lf = (float)localb[idx], rf = (float)remote[idx];
  float part = lf * glw[d] + rf * grw[d];
#pragma unroll
  for (int off = 32; off; off >>= 1) part += __shfl_xor(part, off);
  const float g = 1.f / (1.f + __expf(-part));
  mixed[idx] = (bf16)(g * lf + (1.f - g) * rf);
}

// ---------------- launch ----------------
extern "C" void kernel_launch(void* const* d_in, const int* in_sizes, int n_in,
                              void* d_out, int out_size, void* d_ws, size_t ws_size,
                              hipStream_t stream)
{
  const float* x      = (const float*)d_in[0];
  const float* qkv_w  = (const float*)d_in[1];
  const float* qkv_b  = (const float*)d_in[2];
  const float* rq_w   = (const float*)d_in[3];
  const float* rq_b   = (const float*)d_in[4];
  const float* rkv_w  = (const float*)d_in[5];
  const float* rkv_b  = (const float*)d_in[6];
  const float* rout_w = (const float*)d_in[7];
  const float* rout_b = (const float*)d_in[8];
  const float* out_w  = (const float*)d_in[9];
  const float* out_b  = (const float*)d_in[10];
  const float* gl_w   = (const float*)d_in[11];
  const float* gr_w   = (const float*)d_in[12];

  char* w = (char*)d_ws;
  bf16* qkv_wt = (bf16*)w; w += (size_t)3072 * 1024 * 2;
  bf16* rq_wt  = (bf16*)w; w += (size_t)256 * 1024 * 2;
  bf16* rkv_wt = (bf16*)w; w += (size_t)512 * 1024 * 2;
  bf16* rout_wt= (bf16*)w; w += (size_t)1024 * 256 * 2;
  bf16* out_wt = (bf16*)w; w += (size_t)1024 * 1024 * 2;
  bf16* xb     = (bf16*)w; w += (size_t)B_ * S_ * 1024 * 2;
  bf16* qkvb   = (bf16*)w; w += (size_t)B_ * S_ * 3072 * 2;
  bf16* pooled = (bf16*)w; w += (size_t)B_ * 64 * 1024 * 2;
  bf16* rqb    = (bf16*)w; w += (size_t)B_ * S_ * 256 * 2;
  bf16* rkvb   = (bf16*)w; w += (size_t)B_ * 64 * 512 * 2;
  bf16* latout = (bf16*)w; w += (size_t)B_ * S_ * 256 * 2;
  bf16* remote = (bf16*)w; w += (size_t)B_ * S_ * 1024 * 2;
  bf16* localb = (bf16*)w; w += (size_t)B_ * S_ * 1024 * 2;
  bf16* mixed  = qkvb;  // reuse: qkvb dead after local_attn

  const dim3 tb(32, 8);
  transpose_convert<<<dim3(96, 32), tb, 0, stream>>>(qkv_w, qkv_wt, 1024, 3072);
  transpose_convert<<<dim3(8, 32),  tb, 0, stream>>>(rq_w, rq_wt, 1024, 256);
  transpose_convert<<<dim3(16, 32), tb, 0, stream>>>(rkv_w, rkv_wt, 1024, 512);
  transpose_convert<<<dim3(32, 8),  tb, 0, stream>>>(rout_w, rout_wt, 256, 1024);
  transpose_convert<<<dim3(32, 32), tb, 0, stream>>>(out_w, out_wt, 1024, 1024);
  convert_kernel<<<dim3(2048), 256, 0, stream>>>(x, xb, B_ * S_ * 1024 / 4);

  gemm8_kernel<bf16><<<dim3(32, 12), 512, 0, stream>>>(xb, qkv_wt, qkv_b, qkvb, B_ * S_, 3072, 1024);
  pool_kernel<<<dim3(B_ * 64), 256, 0, stream>>>(x, pooled);
  gemm_bias_kernel<bf16><<<dim3(64, 2), 256, 0, stream>>>(xb, rq_wt, rq_b, rqb, B_ * S_, 256, 1024);
  gemm_bias_kernel<bf16><<<dim3(1, 4), 256, 0, stream>>>(pooled, rkv_wt, rkv_b, rkvb, B_ * 64, 512, 1024);
  latent_attn_kernel<<<dim3(B_ * S_), 256, 0, stream>>>(rqb, rkvb, latout);
  gemm8_kernel<bf16><<<dim3(32, 4), 512, 0, stream>>>(latout, rout_wt, rout_b, remote, B_ * S_, 1024, 256);
  local_attn_mfma<<<dim3(S_ / 128, 16, B_), 256, 0, stream>>>(qkvb, localb);
  gate_mix_kernel<<<dim3(B_ * S_), 1024, 0, stream>>>(localb, remote, gl_w, gr_w, mixed);
  gemm8_kernel<float><<<dim3(32, 4), 512, 0, stream>>>(mixed, out_wt, out_b, (float*)d_out, B_ * S_, 1024, 1024);
}

// Round 6
// 297.875 us; speedup vs baseline: 1.0803x; 1.0803x over previous
//
#include <hip/hip_runtime.h>

typedef __bf16 bf16;
typedef bf16 bf16x4 __attribute__((ext_vector_type(4)));
typedef bf16 bf16x8 __attribute__((ext_vector_type(8)));
typedef float f32x4 __attribute__((ext_vector_type(4)));

#define B_ 2
#define S_ 4096
#define D_ 1024
#define QSTR 3328   // fused qkv+rq row stride

__device__ __forceinline__ void gload_lds16(const void* g, void* l) {
  __builtin_amdgcn_global_load_lds((const __attribute__((address_space(1))) void*)g,
                                   (__attribute__((address_space(3))) void*)l, 16, 0, 0);
}

// ---------------- convert: f32 -> bf16 elementwise ----------------
__global__ __launch_bounds__(256) void convert_kernel(const float* __restrict__ in,
                                                      bf16* __restrict__ out, int n4) {
  for (int i = blockIdx.x * 256 + threadIdx.x; i < n4; i += gridDim.x * 256) {
    const float4 v = ((const float4*)in)[i];
    bf16x4 o = {(bf16)v.x, (bf16)v.y, (bf16)v.z, (bf16)v.w};
    *(bf16x4*)&out[i * 4] = o;
  }
}

// ---------------- transpose+convert: in f32 [K][N] -> out bf16 [N][K] ----------------
__global__ void transpose_convert(const float* __restrict__ in, bf16* __restrict__ out,
                                  int K, int N) {
  __shared__ float tile[32][33];
  const int nb = blockIdx.x * 32;
  const int kb = blockIdx.y * 32;
  const int tx = threadIdx.x, ty = threadIdx.y;
#pragma unroll
  for (int j = 0; j < 4; j++)
    tile[ty + j * 8][tx] = in[(size_t)(kb + ty + j * 8) * N + nb + tx];
  __syncthreads();
#pragma unroll
  for (int j = 0; j < 4; j++)
    out[(size_t)(nb + ty + j * 8) * K + kb + tx] = (bf16)tile[tx][ty + j * 8];
}

// ---------------- 128-tile GEMM (balanced grids for N<=1024 shapes) ----------------
template <typename OutT>
__global__ __launch_bounds__(256) void gemm_bias_kernel(
    const bf16* __restrict__ A, const bf16* __restrict__ Bt,
    const float* __restrict__ bias, OutT* __restrict__ C,
    int M, int N, int K)
{
  __shared__ __align__(16) bf16 Al[128 * 32];
  __shared__ __align__(16) bf16 Bl[128 * 32];
  const int m0 = blockIdx.x * 128;
  const int n0 = blockIdx.y * 128;
  const int t = threadIdx.x;
  const int lane = t & 63;
  const int wave = t >> 6;
  const int wr = (wave >> 1) * 64;
  const int wc = (wave & 1) * 64;
  const int r16 = lane & 15;
  const int kg = lane >> 4;

  f32x4 acc[4][4];
#pragma unroll
  for (int i = 0; i < 4; i++)
#pragma unroll
    for (int j = 0; j < 4; j++) {
      f32x4 z = {0.f, 0.f, 0.f, 0.f};
      acc[i][j] = z;
    }

  for (int k0 = 0; k0 < K; k0 += 32) {
    __syncthreads();
#pragma unroll
    for (int i = 0; i < 2; i++) {
      const int o = i * 4096 + wave * 1024 + lane * 16;
      const int r = o >> 6;
      const int cb = o & 63;
      gload_lds16((const char*)(A + (size_t)(m0 + r) * K + k0) + cb,
                  (char*)Al + i * 4096 + wave * 1024);
      gload_lds16((const char*)(Bt + (size_t)(n0 + r) * K + k0) + cb,
                  (char*)Bl + i * 4096 + wave * 1024);
    }
    __syncthreads();
    bf16x8 a[4], b[4];
#pragma unroll
    for (int i = 0; i < 4; i++)
      a[i] = *(const bf16x8*)&Al[(wr + i * 16 + r16) * 32 + kg * 8];
#pragma unroll
    for (int i = 0; i < 4; i++)
      b[i] = *(const bf16x8*)&Bl[(wc + i * 16 + r16) * 32 + kg * 8];
#pragma unroll
    for (int i = 0; i < 4; i++)
#pragma unroll
      for (int j = 0; j < 4; j++)
        acc[i][j] = __builtin_amdgcn_mfma_f32_16x16x32_bf16(a[i], b[j], acc[i][j], 0, 0, 0);
  }

  float bs[4];
#pragma unroll
  for (int j = 0; j < 4; j++) bs[j] = bias[n0 + wc + j * 16 + r16];
#pragma unroll
  for (int i = 0; i < 4; i++)
#pragma unroll
    for (int j = 0; j < 4; j++)
#pragma unroll
      for (int r = 0; r < 4; r++) {
        const int row = m0 + wr + i * 16 + kg * 4 + r;
        const int col = n0 + wc + j * 16 + r16;
        C[(size_t)row * N + col] = (OutT)(acc[i][j][r] + bs[j]);
      }
}

// ---------------- 256x256 8-phase-style GEMM (swizzled LDS, counted vmcnt, setprio) ----
template <typename OutT>
__global__ __launch_bounds__(512, 1) void gemm8_kernel(
    const bf16* __restrict__ A, const bf16* __restrict__ Bt,
    const float* __restrict__ bias, OutT* __restrict__ C,
    int M, int N, int K)
{
  __shared__ __align__(16) bf16 Al[2][256 * 64];
  __shared__ __align__(16) bf16 Bl[2][256 * 64];

  const int nbx = gridDim.x;
  const int nwg = nbx * gridDim.y;
  int bid = blockIdx.y * nbx + blockIdx.x;
  bid = (bid & 7) * (nwg >> 3) + (bid >> 3);   // XCD swizzle (nwg % 8 == 0)
  const int m0 = (bid % nbx) * 256;
  const int n0 = (bid / nbx) * 256;

  const int t = threadIdx.x;
  const int lane = t & 63;
  const int w = t >> 6;
  const int wm = w >> 2;
  const int wn = w & 3;
  const int l15 = lane & 15;
  const int kg = lane >> 4;

  const int srow = t >> 3;
  const int schunk = (t & 7) ^ (srow & 7);
  const bf16* Asrc = A + (size_t)(m0 + srow) * K + schunk * 8;
  const bf16* Bsrc = Bt + (size_t)(n0 + srow) * K + schunk * 8;
  const int ldsoff = w * 1024;

  const int NT = K >> 6;

  const int arow = wm * 128 + l15;
  const int brow = wn * 64 + l15;
  const int c0 = ((0 * 4 + kg) ^ (l15 & 7)) * 16;
  const int c1 = ((1 * 4 + kg) ^ (l15 & 7)) * 16;

  f32x4 acc[8][4];
#pragma unroll
  for (int i = 0; i < 8; i++)
#pragma unroll
    for (int j = 0; j < 4; j++) { f32x4 z = {0, 0, 0, 0}; acc[i][j] = z; }

  for (int kt = 0; kt < 2 && kt < NT; kt++) {
#pragma unroll
    for (int rd = 0; rd < 4; rd++)
      gload_lds16(Bsrc + (size_t)(rd * 64) * K + kt * 64, (char*)&Bl[kt][0] + rd * 8192 + ldsoff);
#pragma unroll
    for (int rd = 0; rd < 4; rd++)
      gload_lds16(Asrc + (size_t)(rd * 64) * K + kt * 64, (char*)&Al[kt][0] + rd * 8192 + ldsoff);
  }
  asm volatile("s_waitcnt vmcnt(0)" ::: "memory");
  __syncthreads();

  bf16x8 af[4][2], bfr[4][2];

  for (int kt = 0; kt < NT; kt++) {
    const int cur = kt & 1;
    const bool st = (kt + 2) < NT;
    const char* Ab = (const char*)&Al[cur][0];
    const char* Bb = (const char*)&Bl[cur][0];

    // ---- P0
#pragma unroll
    for (int i = 0; i < 4; i++) {
      af[i][0] = *(const bf16x8*)(Ab + (arow + i * 16) * 128 + c0);
      af[i][1] = *(const bf16x8*)(Ab + (arow + i * 16) * 128 + c1);
    }
#pragma unroll
    for (int j = 0; j < 2; j++) {
      bfr[j][0] = *(const bf16x8*)(Bb + (brow + j * 16) * 128 + c0);
      bfr[j][1] = *(const bf16x8*)(Bb + (brow + j * 16) * 128 + c1);
    }
    __builtin_amdgcn_s_barrier();
    asm volatile("s_waitcnt lgkmcnt(0)" ::: "memory");
    __builtin_amdgcn_sched_barrier(0);
    __builtin_amdgcn_s_setprio(1);
#pragma unroll
    for (int i = 0; i < 4; i++)
#pragma unroll
      for (int j = 0; j < 2; j++) {
        acc[i][j] = __builtin_amdgcn_mfma_f32_16x16x32_bf16(af[i][0], bfr[j][0], acc[i][j], 0, 0, 0);
        acc[i][j] = __builtin_amdgcn_mfma_f32_16x16x32_bf16(af[i][1], bfr[j][1], acc[i][j], 0, 0, 0);
      }
    __builtin_amdgcn_s_setprio(0);
    __builtin_amdgcn_s_barrier();

    // ---- P1
#pragma unroll
    for (int j = 2; j < 4; j++) {
      bfr[j][0] = *(const bf16x8*)(Bb + (brow + j * 16) * 128 + c0);
      bfr[j][1] = *(const bf16x8*)(Bb + (brow + j * 16) * 128 + c1);
    }
    __builtin_amdgcn_s_barrier();
    asm volatile("s_waitcnt lgkmcnt(0)" ::: "memory");
    __builtin_amdgcn_sched_barrier(0);
    __builtin_amdgcn_s_setprio(1);
#pragma unroll
    for (int i = 0; i < 4; i++)
#pragma unroll
      for (int j = 2; j < 4; j++) {
        acc[i][j] = __builtin_amdgcn_mfma_f32_16x16x32_bf16(af[i][0], bfr[j][0], acc[i][j], 0, 0, 0);
        acc[i][j] = __builtin_amdgcn_mfma_f32_16x16x32_bf16(af[i][1], bfr[j][1], acc[i][j], 0, 0, 0);
      }
    __builtin_amdgcn_s_setprio(0);
    __builtin_amdgcn_s_barrier();

    // ---- P2
#pragma unroll
    for (int i = 0; i < 4; i++) {
      af[i][0] = *(const bf16x8*)(Ab + (arow + (i + 4) * 16) * 128 + c0);
      af[i][1] = *(const bf16x8*)(Ab + (arow + (i + 4) * 16) * 128 + c1);
    }
    if (st) {
#pragma unroll
      for (int rd = 0; rd < 4; rd++)
        gload_lds16(Bsrc + (size_t)(rd * 64) * K + (kt + 2) * 64, (char*)&Bl[cur][0] + rd * 8192 + ldsoff);
    }
    __builtin_amdgcn_s_barrier();
    asm volatile("s_waitcnt lgkmcnt(0)" ::: "memory");
    __builtin_amdgcn_sched_barrier(0);
    __builtin_amdgcn_s_setprio(1);
#pragma unroll
    for (int i = 0; i < 4; i++)
#pragma unroll
      for (int j = 0; j < 2; j++) {
        acc[i + 4][j] = __builtin_amdgcn_mfma_f32_16x16x32_bf16(af[i][0], bfr[j][0], acc[i + 4][j], 0, 0, 0);
        acc[i + 4][j] = __builtin_amdgcn_mfma_f32_16x16x32_bf16(af[i][1], bfr[j][1], acc[i + 4][j], 0, 0, 0);
      }
    __builtin_amdgcn_s_setprio(0);
    __builtin_amdgcn_s_barrier();

    // ---- P3
    if (st) {
#pragma unroll
      for (int rd = 0; rd < 4; rd++)
        gload_lds16(Asrc + (size_t)(rd * 64) * K + (kt + 2) * 64, (char*)&Al[cur][0] + rd * 8192 + ldsoff);
    }
    __builtin_amdgcn_s_setprio(1);
#pragma unroll
    for (int i = 0; i < 4; i++)
#pragma unroll
      for (int j = 2; j < 4; j++) {
        acc[i + 4][j] = __builtin_amdgcn_mfma_f32_16x16x32_bf16(af[i][0], bfr[j][0], acc[i + 4][j], 0, 0, 0);
        acc[i + 4][j] = __builtin_amdgcn_mfma_f32_16x16x32_bf16(af[i][1], bfr[j][1], acc[i + 4][j], 0, 0, 0);
      }
    __builtin_amdgcn_s_setprio(0);
    if (st) asm volatile("s_waitcnt vmcnt(8)" ::: "memory");
    else    asm volatile("s_waitcnt vmcnt(0)" ::: "memory");
    __builtin_amdgcn_s_barrier();
  }

  float bs[4];
#pragma unroll
  for (int j = 0; j < 4; j++) bs[j] = bias[n0 + wn * 64 + j * 16 + l15];
#pragma unroll
  for (int i = 0; i < 8; i++)
#pragma unroll
    for (int j = 0; j < 4; j++)
#pragma unroll
      for (int rr = 0; rr < 4; rr++) {
        const int row = m0 + wm * 128 + i * 16 + kg * 4 + rr;
        const int col = n0 + wn * 64 + j * 16 + l15;
        C[(size_t)row * N + col] = (OutT)(acc[i][j][rr] + bs[j]);
      }
}

// ---------------- pooling (reads bf16 xb) ----------------
__global__ __launch_bounds__(256) void pool_kernel(const bf16* __restrict__ xb,
                                                   bf16* __restrict__ pooled) {
  const int blk = blockIdx.x;
  const int b = blk >> 6, lt = blk & 63;
  const int t = threadIdx.x;
  for (int d = t; d < D_; d += 256) {
    const bf16* p = xb + ((size_t)b * S_ + lt * 64) * D_ + d;
    float sum = 0.f;
#pragma unroll
    for (int c = 0; c < 64; c++) sum += (float)p[(size_t)c * D_];
    pooled[(size_t)blk * D_ + d] = (bf16)(sum * 0.015625f);
  }
}

// ---------------- latent attention (rq read from fused qkvrb) ----------------
__global__ __launch_bounds__(256) void latent_attn_kernel(
    const bf16* __restrict__ qkvrb, const bf16* __restrict__ rkvb,
    bf16* __restrict__ latout)
{
  __shared__ float rq_s[256];
  __shared__ float attn_s[4][64];
  const int blk = blockIdx.x;
  const int b = blk >> 12, s = blk & 4095;
  const int t = threadIdx.x;
  const int h = t >> 6, l = t & 63;
  const int cid = s >> 6;
  rq_s[t] = (float)qkvrb[((size_t)b * S_ + s) * QSTR + 3072 + t];
  __syncthreads();
  float val = -1e30f;
  if (l < cid) {
    const bf16* kr = rkvb + (size_t)(b * 64 + l) * 512 + h * 64;
    float sum = 0.f;
#pragma unroll
    for (int c = 0; c < 8; c++) {
      bf16x8 kv = *(const bf16x8*)(kr + c * 8);
#pragma unroll
      for (int j = 0; j < 8; j++) sum += rq_s[h * 64 + c * 8 + j] * (float)kv[j];
    }
    val = sum * 0.125f;
  }
  float mx = val;
#pragma unroll
  for (int off = 32; off; off >>= 1) mx = fmaxf(mx, __shfl_xor(mx, off));
  const float p = (l < cid) ? __expf(val - mx) : 0.f;
  float sm = p;
#pragma unroll
  for (int off = 32; off; off >>= 1) sm += __shfl_xor(sm, off);
  attn_s[h][l] = (sm > 0.f) ? p / sm : 0.f;
  __syncthreads();
  float o = 0.f;
  const bf16* vb = rkvb + (size_t)b * 64 * 512 + 256 + h * 64 + l;
  for (int lat = 0; lat < cid; lat++) o += attn_s[h][lat] * (float)vb[(size_t)lat * 512];
  latout[((size_t)b * S_ + s) * 256 + h * 64 + l] = (bf16)o;
}

// ---------------- local windowed attention, MFMA (row stride QSTR) ----------------
__global__ __launch_bounds__(256) void local_attn_mfma(
    const bf16* __restrict__ qkv, bf16* __restrict__ localb)
{
  __shared__ __align__(16) bf16 Kl[128 * 72];
  __shared__ __align__(16) bf16 Vt[64 * 136];
  __shared__ __align__(16) bf16 Pl[4][16 * 136];

  const int q0 = blockIdx.x * 128;
  const int h  = blockIdx.y;
  const int b  = blockIdx.z;
  const int t  = threadIdx.x;
  const int w  = t >> 6;
  const int l  = t & 63;
  const int g  = l >> 4;
  const int l15 = l & 15;

  const bf16* qbase = qkv + (size_t)b * S_ * QSTR + h * 64;
  const bf16* kbase = qbase + 1024;
  const bf16* vbase = qbase + 2048;

  bf16x8 qf[2][2];
#pragma unroll
  for (int qg = 0; qg < 2; qg++)
#pragma unroll
    for (int db = 0; db < 2; db++)
      qf[qg][db] = *(const bf16x8*)(qbase + (size_t)(q0 + w * 32 + qg * 16 + l15) * QSTR + db * 32 + g * 8);

  float m_[2][4], l_[2][4];
  f32x4 accO[2][4];
#pragma unroll
  for (int qg = 0; qg < 2; qg++) {
#pragma unroll
    for (int r = 0; r < 4; r++) { m_[qg][r] = -1e30f; l_[qg][r] = 0.f; }
#pragma unroll
    for (int dt = 0; dt < 4; dt++) { f32x4 z = {0,0,0,0}; accO[qg][dt] = z; }
  }

  const int tstart = (q0 == 0) ? 1 : 0;
  for (int tile = tstart; tile < 2; tile++) {
    const int base = q0 - 128 + tile * 128;
    __syncthreads();
#pragma unroll
    for (int i = 0; i < 4; i++) {
      const int c = i * 256 + t;
      const int k = c >> 3, dc = c & 7;
      *(bf16x8*)&Kl[k * 72 + dc * 8] = *(const bf16x8*)(kbase + (size_t)(base + k) * QSTR + dc * 8);
    }
    {
      const int k = t & 127, dh = (t >> 7) * 32;
#pragma unroll
      for (int i = 0; i < 4; i++) {
        bf16x8 v = *(const bf16x8*)(vbase + (size_t)(base + k) * QSTR + dh + i * 8);
#pragma unroll
        for (int j = 0; j < 8; j++)
          Vt[(dh + i * 8 + j) * 136 + k] = v[j];
      }
    }
    __syncthreads();

    const int kt_lo = (tile == 0) ? 2 * w : 0;
    const int kt_hi = (tile == 0) ? 8 : 2 * w + 2;
    const int nkt = kt_hi - kt_lo;

    f32x4 s[2][8];
#pragma unroll
    for (int qg = 0; qg < 2; qg++)
#pragma unroll
      for (int kk = 0; kk < 8; kk++) { f32x4 z = {0,0,0,0}; s[qg][kk] = z; }

#pragma unroll
    for (int kk = 0; kk < 8; kk++) {
      if (kk >= nkt) continue;
      const int kt = kt_lo + kk;
      const bf16x8 kf0 = *(const bf16x8*)&Kl[(kt * 16 + l15) * 72 + g * 8];
      const bf16x8 kf1 = *(const bf16x8*)&Kl[(kt * 16 + l15) * 72 + 32 + g * 8];
      s[0][kk] = __builtin_amdgcn_mfma_f32_16x16x32_bf16(qf[0][0], kf0, s[0][kk], 0, 0, 0);
      s[0][kk] = __builtin_amdgcn_mfma_f32_16x16x32_bf16(qf[0][1], kf1, s[0][kk], 0, 0, 0);
      s[1][kk] = __builtin_amdgcn_mfma_f32_16x16x32_bf16(qf[1][0], kf0, s[1][kk], 0, 0, 0);
      s[1][kk] = __builtin_amdgcn_mfma_f32_16x16x32_bf16(qf[1][1], kf1, s[1][kk], 0, 0, 0);
    }

#pragma unroll
    for (int qg = 0; qg < 2; qg++) {
#pragma unroll
      for (int kk = 0; kk < 8; kk++) {
        if (kk >= nkt) continue;
        const int kr = (kt_lo + kk) * 16 + l15;
#pragma unroll
        for (int r = 0; r < 4; r++) {
          const int qr = w * 32 + qg * 16 + g * 4 + r;
          const bool ok = (tile == 0) ? (kr >= qr) : (kr < qr);
          s[qg][kk][r] = ok ? s[qg][kk][r] * 0.125f : -1e9f;
        }
      }
      float corr[4];
#pragma unroll
      for (int r = 0; r < 4; r++) {
        float v = -1e30f;
#pragma unroll
        for (int kk = 0; kk < 8; kk++) { if (kk >= nkt) continue; v = fmaxf(v, s[qg][kk][r]); }
        v = fmaxf(v, __shfl_xor(v, 1));
        v = fmaxf(v, __shfl_xor(v, 2));
        v = fmaxf(v, __shfl_xor(v, 4));
        v = fmaxf(v, __shfl_xor(v, 8));
        const float mn = fmaxf(m_[qg][r], v);
        corr[r] = __expf(m_[qg][r] - mn);
        m_[qg][r] = mn;
      }
      float rs[4] = {0.f, 0.f, 0.f, 0.f};
#pragma unroll
      for (int kk = 0; kk < 8; kk++) {
        if (kk >= nkt) continue;
        const int kt = kt_lo + kk;
#pragma unroll
        for (int r = 0; r < 4; r++) {
          const float sv = s[qg][kk][r];
          const float p = (sv > -5e8f) ? __expf(sv - m_[qg][r]) : 0.f;
          rs[r] += p;
          Pl[w][(g * 4 + r) * 136 + kt * 16 + l15] = (bf16)p;
        }
      }
#pragma unroll
      for (int r = 0; r < 4; r++) {
        float v = rs[r];
        v += __shfl_xor(v, 1); v += __shfl_xor(v, 2);
        v += __shfl_xor(v, 4); v += __shfl_xor(v, 8);
        l_[qg][r] = l_[qg][r] * corr[r] + v;
#pragma unroll
        for (int dt = 0; dt < 4; dt++) accO[qg][dt][r] *= corr[r];
      }
      asm volatile("s_waitcnt lgkmcnt(0)" ::: "memory");
      __builtin_amdgcn_sched_barrier(0);
      const int kc_lo = (tile == 0) ? w : 0;
      const int kc_hi = (tile == 0) ? 4 : w + 1;
#pragma unroll
      for (int kc = 0; kc < 4; kc++) {
        if (kc < kc_lo || kc >= kc_hi) continue;
        const bf16x8 pa = *(const bf16x8*)&Pl[w][l15 * 136 + kc * 32 + g * 8];
#pragma unroll
        for (int dt = 0; dt < 4; dt++) {
          const bf16x8 vf = *(const bf16x8*)&Vt[(dt * 16 + l15) * 136 + kc * 32 + g * 8];
          accO[qg][dt] = __builtin_amdgcn_mfma_f32_16x16x32_bf16(pa, vf, accO[qg][dt], 0, 0, 0);
        }
      }
    }
  }

  bf16* outp = localb + ((size_t)b * S_ + q0 + w * 32) * 1024 + h * 64;
#pragma unroll
  for (int qg = 0; qg < 2; qg++)
#pragma unroll
    for (int r = 0; r < 4; r++) {
      const float inv = (l_[qg][r] > 0.f) ? 1.f / l_[qg][r] : 0.f;
#pragma unroll
      for (int dt = 0; dt < 4; dt++)
        outp[(size_t)(qg * 16 + g * 4 + r) * 1024 + dt * 16 + l15] = (bf16)(accO[qg][dt][r] * inv);
    }
}

// ---------------- gate + mix ----------------
__global__ __launch_bounds__(1024) void gate_mix_kernel(
    const bf16* __restrict__ localb, const bf16* __restrict__ remote,
    const float* __restrict__ glw, const float* __restrict__ grw,
    bf16* __restrict__ mixed)
{
  const int blk = blockIdx.x;
  const int b = blk >> 12, s = blk & 4095;
  const int t = threadIdx.x;
  const int d = t & 63;
  const size_t idx = ((size_t)b * S_ + s) * 1024 + t;
  const float lf = (float)localb[idx], rf = (float)remote[idx];
  float part = lf * glw[d] + rf * grw[d];
#pragma unroll
  for (int off = 32; off; off >>= 1) part += __shfl_xor(part, off);
  const float g = 1.f / (1.f + __expf(-part));
  mixed[idx] = (bf16)(g * lf + (1.f - g) * rf);
}

// ---------------- launch ----------------
extern "C" void kernel_launch(void* const* d_in, const int* in_sizes, int n_in,
                              void* d_out, int out_size, void* d_ws, size_t ws_size,
                              hipStream_t stream)
{
  const float* x      = (const float*)d_in[0];
  const float* qkv_w  = (const float*)d_in[1];
  const float* qkv_b  = (const float*)d_in[2];
  const float* rq_w   = (const float*)d_in[3];
  const float* rq_b   = (const float*)d_in[4];
  const float* rkv_w  = (const float*)d_in[5];
  const float* rkv_b  = (const float*)d_in[6];
  const float* rout_w = (const float*)d_in[7];
  const float* rout_b = (const float*)d_in[8];
  const float* out_w  = (const float*)d_in[9];
  const float* out_b  = (const float*)d_in[10];
  const float* gl_w   = (const float*)d_in[11];
  const float* gr_w   = (const float*)d_in[12];

  char* w = (char*)d_ws;
  bf16* qkvr_wt = (bf16*)w; w += (size_t)QSTR * 1024 * 2;       // fused qkv+rq weights [3328][1024]
  bf16* rkv_wt  = (bf16*)w; w += (size_t)512 * 1024 * 2;
  bf16* rout_wt = (bf16*)w; w += (size_t)1024 * 256 * 2;
  bf16* out_wt  = (bf16*)w; w += (size_t)1024 * 1024 * 2;
  float* qkvr_b = (float*)w; w += (size_t)QSTR * 4;             // fused bias
  bf16* xb      = (bf16*)w; w += (size_t)B_ * S_ * 1024 * 2;
  bf16* qkvrb   = (bf16*)w; w += (size_t)B_ * S_ * QSTR * 2;    // fused activations
  bf16* pooled  = (bf16*)w; w += (size_t)B_ * 64 * 1024 * 2;
  bf16* rkvb    = (bf16*)w; w += (size_t)B_ * 64 * 512 * 2;
  bf16* latout  = (bf16*)w; w += (size_t)B_ * S_ * 256 * 2;
  bf16* remote  = (bf16*)w; w += (size_t)B_ * S_ * 1024 * 2;
  bf16* localb  = (bf16*)w; w += (size_t)B_ * S_ * 1024 * 2;
  bf16* mixed   = qkvrb;  // reuse: qkvrb dead after local_attn + latent

  hipMemcpyAsync(qkvr_b, qkv_b, 3072 * sizeof(float), hipMemcpyDeviceToDevice, stream);
  hipMemcpyAsync(qkvr_b + 3072, rq_b, 256 * sizeof(float), hipMemcpyDeviceToDevice, stream);

  const dim3 tb(32, 8);
  transpose_convert<<<dim3(96, 32), tb, 0, stream>>>(qkv_w, qkvr_wt, 1024, 3072);
  transpose_convert<<<dim3(8, 32),  tb, 0, stream>>>(rq_w, qkvr_wt + (size_t)3072 * 1024, 1024, 256);
  transpose_convert<<<dim3(16, 32), tb, 0, stream>>>(rkv_w, rkv_wt, 1024, 512);
  transpose_convert<<<dim3(32, 8),  tb, 0, stream>>>(rout_w, rout_wt, 256, 1024);
  transpose_convert<<<dim3(32, 32), tb, 0, stream>>>(out_w, out_wt, 1024, 1024);
  convert_kernel<<<dim3(2048), 256, 0, stream>>>(x, xb, B_ * S_ * 1024 / 4);

  // fused qkv+rq GEMM: [8192 x 3328] = xb[8192x1024] @ qkvr_wt^T
  gemm8_kernel<bf16><<<dim3(32, 13), 512, 0, stream>>>(xb, qkvr_wt, qkvr_b, qkvrb, B_ * S_, QSTR, 1024);
  pool_kernel<<<dim3(B_ * 64), 256, 0, stream>>>(xb, pooled);
  gemm_bias_kernel<bf16><<<dim3(1, 4), 256, 0, stream>>>(pooled, rkv_wt, rkv_b, rkvb, B_ * 64, 512, 1024);
  latent_attn_kernel<<<dim3(B_ * S_), 256, 0, stream>>>(qkvrb, rkvb, latout);
  gemm_bias_kernel<bf16><<<dim3(64, 8), 256, 0, stream>>>(latout, rout_wt, rout_b, remote, B_ * S_, 1024, 256);
  local_attn_mfma<<<dim3(S_ / 128, 16, B_), 256, 0, stream>>>(qkvrb, localb);
  gate_mix_kernel<<<dim3(B_ * S_), 1024, 0, stream>>>(localb, remote, gl_w, gr_w, mixed);
  gemm_bias_kernel<float><<<dim3(64, 8), 256, 0, stream>>>(mixed, out_wt, out_b, (float*)d_out, B_ * S_, 1024, 1024);
}

// Round 7
// 293.656 us; speedup vs baseline: 1.0958x; 1.0144x over previous
//
#include <hip/hip_runtime.h>

typedef __bf16 bf16;
typedef bf16 bf16x4 __attribute__((ext_vector_type(4)));
typedef bf16 bf16x8 __attribute__((ext_vector_type(8)));
typedef float f32x4 __attribute__((ext_vector_type(4)));

#define B_ 2
#define S_ 4096
#define D_ 1024
#define QSTR 3328   // fused qkv+rq row stride

__device__ __forceinline__ void gload_lds16(const void* g, void* l) {
  __builtin_amdgcn_global_load_lds((const __attribute__((address_space(1))) void*)g,
                                   (__attribute__((address_space(3))) void*)l, 16, 0, 0);
}

// ---------------- convert: f32 -> bf16 elementwise ----------------
__global__ __launch_bounds__(256) void convert_kernel(const float* __restrict__ in,
                                                      bf16* __restrict__ out, int n4) {
  for (int i = blockIdx.x * 256 + threadIdx.x; i < n4; i += gridDim.x * 256) {
    const float4 v = ((const float4*)in)[i];
    bf16x4 o = {(bf16)v.x, (bf16)v.y, (bf16)v.z, (bf16)v.w};
    *(bf16x4*)&out[i * 4] = o;
  }
}

// ---------------- transpose+convert: in f32 [K][N] -> out bf16 [N][K] ----------------
__global__ void transpose_convert(const float* __restrict__ in, bf16* __restrict__ out,
                                  int K, int N) {
  __shared__ float tile[32][33];
  const int nb = blockIdx.x * 32;
  const int kb = blockIdx.y * 32;
  const int tx = threadIdx.x, ty = threadIdx.y;
#pragma unroll
  for (int j = 0; j < 4; j++)
    tile[ty + j * 8][tx] = in[(size_t)(kb + ty + j * 8) * N + nb + tx];
  __syncthreads();
#pragma unroll
  for (int j = 0; j < 4; j++)
    out[(size_t)(nb + ty + j * 8) * K + kb + tx] = (bf16)tile[tx][ty + j * 8];
}

// ---------------- 128-tile GEMM (balanced grids for N<=1024 shapes) ----------------
template <typename OutT>
__global__ __launch_bounds__(256) void gemm_bias_kernel(
    const bf16* __restrict__ A, const bf16* __restrict__ Bt,
    const float* __restrict__ bias, OutT* __restrict__ C,
    int M, int N, int K)
{
  __shared__ __align__(16) bf16 Al[128 * 32];
  __shared__ __align__(16) bf16 Bl[128 * 32];
  const int m0 = blockIdx.x * 128;
  const int n0 = blockIdx.y * 128;
  const int t = threadIdx.x;
  const int lane = t & 63;
  const int wave = t >> 6;
  const int wr = (wave >> 1) * 64;
  const int wc = (wave & 1) * 64;
  const int r16 = lane & 15;
  const int kg = lane >> 4;

  f32x4 acc[4][4];
#pragma unroll
  for (int i = 0; i < 4; i++)
#pragma unroll
    for (int j = 0; j < 4; j++) {
      f32x4 z = {0.f, 0.f, 0.f, 0.f};
      acc[i][j] = z;
    }

  for (int k0 = 0; k0 < K; k0 += 32) {
    __syncthreads();
#pragma unroll
    for (int i = 0; i < 2; i++) {
      const int o = i * 4096 + wave * 1024 + lane * 16;
      const int r = o >> 6;
      const int cb = o & 63;
      gload_lds16((const char*)(A + (size_t)(m0 + r) * K + k0) + cb,
                  (char*)Al + i * 4096 + wave * 1024);
      gload_lds16((const char*)(Bt + (size_t)(n0 + r) * K + k0) + cb,
                  (char*)Bl + i * 4096 + wave * 1024);
    }
    __syncthreads();
    bf16x8 a[4], b[4];
#pragma unroll
    for (int i = 0; i < 4; i++)
      a[i] = *(const bf16x8*)&Al[(wr + i * 16 + r16) * 32 + kg * 8];
#pragma unroll
    for (int i = 0; i < 4; i++)
      b[i] = *(const bf16x8*)&Bl[(wc + i * 16 + r16) * 32 + kg * 8];
#pragma unroll
    for (int i = 0; i < 4; i++)
#pragma unroll
      for (int j = 0; j < 4; j++)
        acc[i][j] = __builtin_amdgcn_mfma_f32_16x16x32_bf16(a[i], b[j], acc[i][j], 0, 0, 0);
  }

  float bs[4];
#pragma unroll
  for (int j = 0; j < 4; j++) bs[j] = bias[n0 + wc + j * 16 + r16];
#pragma unroll
  for (int i = 0; i < 4; i++)
#pragma unroll
    for (int j = 0; j < 4; j++)
#pragma unroll
      for (int r = 0; r < 4; r++) {
        const int row = m0 + wr + i * 16 + kg * 4 + r;
        const int col = n0 + wc + j * 16 + r16;
        C[(size_t)row * N + col] = (OutT)(acc[i][j][r] + bs[j]);
      }
}

// ---------------- 256x256 true-8-phase GEMM (T2+T3+T4+T5) ----------------
// BK=64, 512 thr (8 waves 2Mx4N), per-wave 128x64 out, dbuf 128 KiB LDS.
// Per iter: 2 K-tiles, 8 phases, 16 MFMA/phase/wave, 1 quarter-tile staged/phase
// (Ph8: 4 quarters). Counted vmcnt(6)@Ph4, vmcnt(8)@Ph8 -- never 0 in loop.
template <typename OutT>
__global__ __launch_bounds__(512, 1) void gemm8_kernel(
    const bf16* __restrict__ A, const bf16* __restrict__ Bt,
    const float* __restrict__ bias, OutT* __restrict__ C,
    int M, int N, int K)
{
  __shared__ __align__(16) bf16 Al[2][256 * 64];
  __shared__ __align__(16) bf16 Bl[2][256 * 64];

  const int nbx = gridDim.x;
  const int nwg = nbx * gridDim.y;
  int bid = blockIdx.y * nbx + blockIdx.x;
  bid = (bid & 7) * (nwg >> 3) + (bid >> 3);   // XCD swizzle (nwg % 8 == 0)
  const int m0 = (bid % nbx) * 256;
  const int n0 = (bid / nbx) * 256;

  const int t = threadIdx.x;
  const int lane = t & 63;
  const int w = t >> 6;
  const int wm = w >> 2;
  const int wn = w & 3;
  const int l15 = lane & 15;
  const int kg = lane >> 4;

  // staging: quarter = 64 rows x 64 cols (8KB), 1 gload_lds/thread/quarter
  const int srow = t >> 3;                       // 0..63 row within quarter
  const int schunk = (t & 7) ^ (srow & 7);       // pre-swizzled source chunk
  const bf16* Aaddr = A + (size_t)(m0 + srow) * K + schunk * 8;
  const bf16* Baddr = Bt + (size_t)(n0 + srow) * K + schunk * 8;

  const int NT = K >> 6;
  const int NITER = NT >> 1;

  const int arow = wm * 128 + l15;   // + aq*64 + ii*16
  const int brow = wn * 64 + l15;    // + jj*16
  const int c0 = (kg ^ (l15 & 7)) * 16;
  const int c1 = ((4 + kg) ^ (l15 & 7)) * 16;

  f32x4 acc[8][4];
#pragma unroll
  for (int i = 0; i < 8; i++)
#pragma unroll
    for (int j = 0; j < 4; j++) { f32x4 z = {0, 0, 0, 0}; acc[i][j] = z; }

#define STG_A(buf, q, kt) gload_lds16(Aaddr + (size_t)(q) * 64 * K + (kt) * 64, \
                                      (char*)&Al[buf][0] + (q) * 8192 + w * 1024)
#define STG_B(buf, q, kt) gload_lds16(Baddr + (size_t)(q) * 64 * K + (kt) * 64, \
                                      (char*)&Bl[buf][0] + (q) * 8192 + w * 1024)
#define RD_A(buf, aq) \
  _Pragma("unroll") for (int ii = 0; ii < 4; ii++) { \
    const char* p_ = (const char*)&Al[buf][0] + (size_t)(arow + (aq) * 64 + ii * 16) * 128; \
    af[ii][0] = *(const bf16x8*)(p_ + c0); \
    af[ii][1] = *(const bf16x8*)(p_ + c1); }
#define RD_B(buf) \
  _Pragma("unroll") for (int jj = 0; jj < 4; jj++) { \
    const char* p_ = (const char*)&Bl[buf][0] + (size_t)(brow + jj * 16) * 128; \
    bfr[jj][0] = *(const bf16x8*)(p_ + c0); \
    bfr[jj][1] = *(const bf16x8*)(p_ + c1); }
#define MM(iofs, j0) \
  _Pragma("unroll") for (int ii = 0; ii < 4; ii++) \
  _Pragma("unroll") for (int jj = (j0); jj < (j0) + 2; jj++) { \
    acc[(iofs) + ii][jj] = __builtin_amdgcn_mfma_f32_16x16x32_bf16(af[ii][0], bfr[jj][0], acc[(iofs) + ii][jj], 0, 0, 0); \
    acc[(iofs) + ii][jj] = __builtin_amdgcn_mfma_f32_16x16x32_bf16(af[ii][1], bfr[jj][1], acc[(iofs) + ii][jj], 0, 0, 0); }
#define BARX __builtin_amdgcn_s_barrier()
#define LGKM0 do { asm volatile("s_waitcnt lgkmcnt(0)" ::: "memory"); \
                   __builtin_amdgcn_sched_barrier(0); } while (0)
#define PRI1 __builtin_amdgcn_s_setprio(1)
#define PRI0 __builtin_amdgcn_s_setprio(0)

  // prologue: stage K-tiles 0 (buf0) and 1 (buf1), 8 quarters each
#pragma unroll
  for (int q = 0; q < 4; q++) { STG_B(0, q, 0); }
#pragma unroll
  for (int q = 0; q < 4; q++) { STG_A(0, q, 0); }
#pragma unroll
  for (int q = 0; q < 4; q++) { STG_B(1, q, 1); }
#pragma unroll
  for (int q = 0; q < 4; q++) { STG_A(1, q, 1); }
  asm volatile("s_waitcnt vmcnt(8)" ::: "memory");  // buf0 landed; buf1 may fly
  BARX;

  bf16x8 af[4][2], bfr[4][2];

  for (int it = 0; it < NITER; it++) {
    const int kt0 = 2 * it;
    const bool st = (it + 1) < NITER;

    // ===== K-tile kt0 (buf0) =====
    // Ph1: read A-quad0 + all B; MFMA q(a0,b01)
    RD_A(0, 0); RD_B(0);
    BARX; LGKM0; PRI1; MM(0, 0); PRI0; BARX;
    // Ph2: stage buf0.B q0,q1 <- kt0+2 (B freed Ph1); MFMA q(a0,b23)
    if (st) { STG_B(0, 0, kt0 + 2); STG_B(0, 1, kt0 + 2); }
    PRI1; MM(0, 2); PRI0; BARX;
    // Ph3: read A-quad1; stage buf0.B q2,q3; MFMA q(a1,b01)
    RD_A(0, 1);
    if (st) { STG_B(0, 2, kt0 + 2); STG_B(0, 3, kt0 + 2); }
    BARX; LGKM0; PRI1; MM(4, 0); PRI0; BARX;
    // Ph4: stage buf0.A q0,q2 (freed Ph1); MFMA q(a1,b23); vmcnt(6)
    if (st) { STG_A(0, 0, kt0 + 2); STG_A(0, 2, kt0 + 2); }
    PRI1; MM(4, 2); PRI0;
    asm volatile("s_waitcnt vmcnt(6)" ::: "memory");   // prev buf1 stages landed
    BARX;

    // ===== K-tile kt0+1 (buf1) =====
    // Ph5: read A-quad0 + all B from buf1; stage buf0.A q1,q3 (freed Ph3)
    RD_A(1, 0); RD_B(1);
    if (st) { STG_A(0, 1, kt0 + 2); STG_A(0, 3, kt0 + 2); }
    BARX; LGKM0; PRI1; MM(0, 0); PRI0; BARX;
    // Ph6: stage buf1.B q0,q1 <- kt0+3 (freed Ph5); MFMA q(a0,b23)
    if (st) { STG_B(1, 0, kt0 + 3); STG_B(1, 1, kt0 + 3); }
    PRI1; MM(0, 2); PRI0; BARX;
    // Ph7: read A-quad1 buf1; stage buf1.B q2,q3; MFMA q(a1,b01)
    RD_A(1, 1);
    if (st) { STG_B(1, 2, kt0 + 3); STG_B(1, 3, kt0 + 3); }
    BARX; LGKM0; PRI1; MM(4, 0); PRI0; BARX;
    // Ph8: stage buf1.A q0-q3 (q0,q2 freed Ph5; q1,q3 freed Ph7); MFMA; vmcnt(8)
    if (st) { STG_A(1, 0, kt0 + 3); STG_A(1, 1, kt0 + 3);
              STG_A(1, 2, kt0 + 3); STG_A(1, 3, kt0 + 3); }
    PRI1; MM(4, 2); PRI0;
    asm volatile("s_waitcnt vmcnt(8)" ::: "memory");   // buf0 stages thru Ph5 landed
    BARX;
  }

#undef STG_A
#undef STG_B
#undef RD_A
#undef RD_B
#undef MM
#undef BARX
#undef LGKM0
#undef PRI1
#undef PRI0

  float bs[4];
#pragma unroll
  for (int j = 0; j < 4; j++) bs[j] = bias[n0 + wn * 64 + j * 16 + l15];
#pragma unroll
  for (int i = 0; i < 8; i++)
#pragma unroll
    for (int j = 0; j < 4; j++)
#pragma unroll
      for (int rr = 0; rr < 4; rr++) {
        const int row = m0 + wm * 128 + i * 16 + kg * 4 + rr;
        const int col = n0 + wn * 64 + j * 16 + l15;
        C[(size_t)row * N + col] = (OutT)(acc[i][j][rr] + bs[j]);
      }
}

// ---------------- pooling (reads bf16 xb) ----------------
__global__ __launch_bounds__(256) void pool_kernel(const bf16* __restrict__ xb,
                                                   bf16* __restrict__ pooled) {
  const int blk = blockIdx.x;
  const int b = blk >> 6, lt = blk & 63;
  const int t = threadIdx.x;
  for (int d = t; d < D_; d += 256) {
    const bf16* p = xb + ((size_t)b * S_ + lt * 64) * D_ + d;
    float sum = 0.f;
#pragma unroll
    for (int c = 0; c < 64; c++) sum += (float)p[(size_t)c * D_];
    pooled[(size_t)blk * D_ + d] = (bf16)(sum * 0.015625f);
  }
}

// ---------------- latent attention (rq read from fused qkvrb) ----------------
__global__ __launch_bounds__(256) void latent_attn_kernel(
    const bf16* __restrict__ qkvrb, const bf16* __restrict__ rkvb,
    bf16* __restrict__ latout)
{
  __shared__ float rq_s[256];
  __shared__ float attn_s[4][64];
  const int blk = blockIdx.x;
  const int b = blk >> 12, s = blk & 4095;
  const int t = threadIdx.x;
  const int h = t >> 6, l = t & 63;
  const int cid = s >> 6;
  rq_s[t] = (float)qkvrb[((size_t)b * S_ + s) * QSTR + 3072 + t];
  __syncthreads();
  float val = -1e30f;
  if (l < cid) {
    const bf16* kr = rkvb + (size_t)(b * 64 + l) * 512 + h * 64;
    float sum = 0.f;
#pragma unroll
    for (int c = 0; c < 8; c++) {
      bf16x8 kv = *(const bf16x8*)(kr + c * 8);
#pragma unroll
      for (int j = 0; j < 8; j++) sum += rq_s[h * 64 + c * 8 + j] * (float)kv[j];
    }
    val = sum * 0.125f;
  }
  float mx = val;
#pragma unroll
  for (int off = 32; off; off >>= 1) mx = fmaxf(mx, __shfl_xor(mx, off));
  const float p = (l < cid) ? __expf(val - mx) : 0.f;
  float sm = p;
#pragma unroll
  for (int off = 32; off; off >>= 1) sm += __shfl_xor(sm, off);
  attn_s[h][l] = (sm > 0.f) ? p / sm : 0.f;
  __syncthreads();
  float o = 0.f;
  const bf16* vb = rkvb + (size_t)b * 64 * 512 + 256 + h * 64 + l;
  for (int lat = 0; lat < cid; lat++) o += attn_s[h][lat] * (float)vb[(size_t)lat * 512];
  latout[((size_t)b * S_ + s) * 256 + h * 64 + l] = (bf16)o;
}

// ---------------- local windowed attention, MFMA (row stride QSTR) ----------------
__global__ __launch_bounds__(256) void local_attn_mfma(
    const bf16* __restrict__ qkv, bf16* __restrict__ localb)
{
  __shared__ __align__(16) bf16 Kl[128 * 72];
  __shared__ __align__(16) bf16 Vt[64 * 136];
  __shared__ __align__(16) bf16 Pl[4][16 * 136];

  const int q0 = blockIdx.x * 128;
  const int h  = blockIdx.y;
  const int b  = blockIdx.z;
  const int t  = threadIdx.x;
  const int w  = t >> 6;
  const int l  = t & 63;
  const int g  = l >> 4;
  const int l15 = l & 15;

  const bf16* qbase = qkv + (size_t)b * S_ * QSTR + h * 64;
  const bf16* kbase = qbase + 1024;
  const bf16* vbase = qbase + 2048;

  bf16x8 qf[2][2];
#pragma unroll
  for (int qg = 0; qg < 2; qg++)
#pragma unroll
    for (int db = 0; db < 2; db++)
      qf[qg][db] = *(const bf16x8*)(qbase + (size_t)(q0 + w * 32 + qg * 16 + l15) * QSTR + db * 32 + g * 8);

  float m_[2][4], l_[2][4];
  f32x4 accO[2][4];
#pragma unroll
  for (int qg = 0; qg < 2; qg++) {
#pragma unroll
    for (int r = 0; r < 4; r++) { m_[qg][r] = -1e30f; l_[qg][r] = 0.f; }
#pragma unroll
    for (int dt = 0; dt < 4; dt++) { f32x4 z = {0,0,0,0}; accO[qg][dt] = z; }
  }

  const int tstart = (q0 == 0) ? 1 : 0;
  for (int tile = tstart; tile < 2; tile++) {
    const int base = q0 - 128 + tile * 128;
    __syncthreads();
#pragma unroll
    for (int i = 0; i < 4; i++) {
      const int c = i * 256 + t;
      const int k = c >> 3, dc = c & 7;
      *(bf16x8*)&Kl[k * 72 + dc * 8] = *(const bf16x8*)(kbase + (size_t)(base + k) * QSTR + dc * 8);
    }
    {
      const int k = t & 127, dh = (t >> 7) * 32;
#pragma unroll
      for (int i = 0; i < 4; i++) {
        bf16x8 v = *(const bf16x8*)(vbase + (size_t)(base + k) * QSTR + dh + i * 8);
#pragma unroll
        for (int j = 0; j < 8; j++)
          Vt[(dh + i * 8 + j) * 136 + k] = v[j];
      }
    }
    __syncthreads();

    const int kt_lo = (tile == 0) ? 2 * w : 0;
    const int kt_hi = (tile == 0) ? 8 : 2 * w + 2;
    const int nkt = kt_hi - kt_lo;

    f32x4 s[2][8];
#pragma unroll
    for (int qg = 0; qg < 2; qg++)
#pragma unroll
      for (int kk = 0; kk < 8; kk++) { f32x4 z = {0,0,0,0}; s[qg][kk] = z; }

#pragma unroll
    for (int kk = 0; kk < 8; kk++) {
      if (kk >= nkt) continue;
      const int kt = kt_lo + kk;
      const bf16x8 kf0 = *(const bf16x8*)&Kl[(kt * 16 + l15) * 72 + g * 8];
      const bf16x8 kf1 = *(const bf16x8*)&Kl[(kt * 16 + l15) * 72 + 32 + g * 8];
      s[0][kk] = __builtin_amdgcn_mfma_f32_16x16x32_bf16(qf[0][0], kf0, s[0][kk], 0, 0, 0);
      s[0][kk] = __builtin_amdgcn_mfma_f32_16x16x32_bf16(qf[0][1], kf1, s[0][kk], 0, 0, 0);
      s[1][kk] = __builtin_amdgcn_mfma_f32_16x16x32_bf16(qf[1][0], kf0, s[1][kk], 0, 0, 0);
      s[1][kk] = __builtin_amdgcn_mfma_f32_16x16x32_bf16(qf[1][1], kf1, s[1][kk], 0, 0, 0);
    }

#pragma unroll
    for (int qg = 0; qg < 2; qg++) {
#pragma unroll
      for (int kk = 0; kk < 8; kk++) {
        if (kk >= nkt) continue;
        const int kr = (kt_lo + kk) * 16 + l15;
#pragma unroll
        for (int r = 0; r < 4; r++) {
          const int qr = w * 32 + qg * 16 + g * 4 + r;
          const bool ok = (tile == 0) ? (kr >= qr) : (kr < qr);
          s[qg][kk][r] = ok ? s[qg][kk][r] * 0.125f : -1e9f;
        }
      }
      float corr[4];
#pragma unroll
      for (int r = 0; r < 4; r++) {
        float v = -1e30f;
#pragma unroll
        for (int kk = 0; kk < 8; kk++) { if (kk >= nkt) continue; v = fmaxf(v, s[qg][kk][r]); }
        v = fmaxf(v, __shfl_xor(v, 1));
        v = fmaxf(v, __shfl_xor(v, 2));
        v = fmaxf(v, __shfl_xor(v, 4));
        v = fmaxf(v, __shfl_xor(v, 8));
        const float mn = fmaxf(m_[qg][r], v);
        corr[r] = __expf(m_[qg][r] - mn);
        m_[qg][r] = mn;
      }
      float rs[4] = {0.f, 0.f, 0.f, 0.f};
#pragma unroll
      for (int kk = 0; kk < 8; kk++) {
        if (kk >= nkt) continue;
        const int kt = kt_lo + kk;
#pragma unroll
        for (int r = 0; r < 4; r++) {
          const float sv = s[qg][kk][r];
          const float p = (sv > -5e8f) ? __expf(sv - m_[qg][r]) : 0.f;
          rs[r] += p;
          Pl[w][(g * 4 + r) * 136 + kt * 16 + l15] = (bf16)p;
        }
      }
#pragma unroll
      for (int r = 0; r < 4; r++) {
        float v = rs[r];
        v += __shfl_xor(v, 1); v += __shfl_xor(v, 2);
        v += __shfl_xor(v, 4); v += __shfl_xor(v, 8);
        l_[qg][r] = l_[qg][r] * corr[r] + v;
#pragma unroll
        for (int dt = 0; dt < 4; dt++) accO[qg][dt][r] *= corr[r];
      }
      asm volatile("s_waitcnt lgkmcnt(0)" ::: "memory");
      __builtin_amdgcn_sched_barrier(0);
      const int kc_lo = (tile == 0) ? w : 0;
      const int kc_hi = (tile == 0) ? 4 : w + 1;
#pragma unroll
      for (int kc = 0; kc < 4; kc++) {
        if (kc < kc_lo || kc >= kc_hi) continue;
        const bf16x8 pa = *(const bf16x8*)&Pl[w][l15 * 136 + kc * 32 + g * 8];
#pragma unroll
        for (int dt = 0; dt < 4; dt++) {
          const bf16x8 vf = *(const bf16x8*)&Vt[(dt * 16 + l15) * 136 + kc * 32 + g * 8];
          accO[qg][dt] = __builtin_amdgcn_mfma_f32_16x16x32_bf16(pa, vf, accO[qg][dt], 0, 0, 0);
        }
      }
    }
  }

  bf16* outp = localb + ((size_t)b * S_ + q0 + w * 32) * 1024 + h * 64;
#pragma unroll
  for (int qg = 0; qg < 2; qg++)
#pragma unroll
    for (int r = 0; r < 4; r++) {
      const float inv = (l_[qg][r] > 0.f) ? 1.f / l_[qg][r] : 0.f;
#pragma unroll
      for (int dt = 0; dt < 4; dt++)
        outp[(size_t)(qg * 16 + g * 4 + r) * 1024 + dt * 16 + l15] = (bf16)(accO[qg][dt][r] * inv);
    }
}

// ---------------- gate + mix ----------------
__global__ __launch_bounds__(1024) void gate_mix_kernel(
    const bf16* __restrict__ localb, const bf16* __restrict__ remote,
    const float* __restrict__ glw, const float* __restrict__ grw,
    bf16* __restrict__ mixed)
{
  const int blk = blockIdx.x;
  const int b = blk >> 12, s = blk & 4095;
  const int t = threadIdx.x;
  const int d = t & 63;
  const size_t idx = ((size_t)b * S_ + s) * 1024 + t;
  const float lf = (float)localb[idx], rf = (float)remote[idx];
  float part = lf * glw[d] + rf * grw[d];
#pragma unroll
  for (int off = 32; off; off >>= 1) part += __shfl_xor(part, off);
  const float g = 1.f / (1.f + __expf(-part));
  mixed[idx] = (bf16)(g * lf + (1.f - g) * rf);
}

// ---------------- launch ----------------
extern "C" void kernel_launch(void* const* d_in, const int* in_sizes, int n_in,
                              void* d_out, int out_size, void* d_ws, size_t ws_size,
                              hipStream_t stream)
{
  const float* x      = (const float*)d_in[0];
  const float* qkv_w  = (const float*)d_in[1];
  const float* qkv_b  = (const float*)d_in[2];
  const float* rq_w   = (const float*)d_in[3];
  const float* rq_b   = (const float*)d_in[4];
  const float* rkv_w  = (const float*)d_in[5];
  const float* rkv_b  = (const float*)d_in[6];
  const float* rout_w = (const float*)d_in[7];
  const float* rout_b = (const float*)d_in[8];
  const float* out_w  = (const float*)d_in[9];
  const float* out_b  = (const float*)d_in[10];
  const float* gl_w   = (const float*)d_in[11];
  const float* gr_w   = (const float*)d_in[12];

  char* w = (char*)d_ws;
  bf16* qkvr_wt = (bf16*)w; w += (size_t)QSTR * 1024 * 2;       // fused qkv+rq weights [3328][1024]
  bf16* rkv_wt  = (bf16*)w; w += (size_t)512 * 1024 * 2;
  bf16* rout_wt = (bf16*)w; w += (size_t)1024 * 256 * 2;
  bf16* out_wt  = (bf16*)w; w += (size_t)1024 * 1024 * 2;
  float* qkvr_b = (float*)w; w += (size_t)QSTR * 4;             // fused bias
  bf16* xb      = (bf16*)w; w += (size_t)B_ * S_ * 1024 * 2;
  bf16* qkvrb   = (bf16*)w; w += (size_t)B_ * S_ * QSTR * 2;    // fused activations
  bf16* pooled  = (bf16*)w; w += (size_t)B_ * 64 * 1024 * 2;
  bf16* rkvb    = (bf16*)w; w += (size_t)B_ * 64 * 512 * 2;
  bf16* latout  = (bf16*)w; w += (size_t)B_ * S_ * 256 * 2;
  bf16* remote  = (bf16*)w; w += (size_t)B_ * S_ * 1024 * 2;
  bf16* localb  = (bf16*)w; w += (size_t)B_ * S_ * 1024 * 2;
  bf16* mixed   = qkvrb;  // reuse: qkvrb dead after local_attn + latent

  hipMemcpyAsync(qkvr_b, qkv_b, 3072 * sizeof(float), hipMemcpyDeviceToDevice, stream);
  hipMemcpyAsync(qkvr_b + 3072, rq_b, 256 * sizeof(float), hipMemcpyDeviceToDevice, stream);

  const dim3 tb(32, 8);
  transpose_convert<<<dim3(96, 32), tb, 0, stream>>>(qkv_w, qkvr_wt, 1024, 3072);
  transpose_convert<<<dim3(8, 32),  tb, 0, stream>>>(rq_w, qkvr_wt + (size_t)3072 * 1024, 1024, 256);
  transpose_convert<<<dim3(16, 32), tb, 0, stream>>>(rkv_w, rkv_wt, 1024, 512);
  transpose_convert<<<dim3(32, 8),  tb, 0, stream>>>(rout_w, rout_wt, 256, 1024);
  transpose_convert<<<dim3(32, 32), tb, 0, stream>>>(out_w, out_wt, 1024, 1024);
  convert_kernel<<<dim3(2048), 256, 0, stream>>>(x, xb, B_ * S_ * 1024 / 4);

  // fused qkv+rq GEMM: [8192 x 3328] = xb[8192x1024] @ qkvr_wt^T
  gemm8_kernel<bf16><<<dim3(32, 13), 512, 0, stream>>>(xb, qkvr_wt, qkvr_b, qkvrb, B_ * S_, QSTR, 1024);
  pool_kernel<<<dim3(B_ * 64), 256, 0, stream>>>(xb, pooled);
  gemm_bias_kernel<bf16><<<dim3(1, 4), 256, 0, stream>>>(pooled, rkv_wt, rkv_b, rkvb, B_ * 64, 512, 1024);
  latent_attn_kernel<<<dim3(B_ * S_), 256, 0, stream>>>(qkvrb, rkvb, latout);
  gemm_bias_kernel<bf16><<<dim3(64, 8), 256, 0, stream>>>(latout, rout_wt, rout_b, remote, B_ * S_, 1024, 256);
  local_attn_mfma<<<dim3(S_ / 128, 16, B_), 256, 0, stream>>>(qkvrb, localb);
  gate_mix_kernel<<<dim3(B_ * S_), 1024, 0, stream>>>(localb, remote, gl_w, gr_w, mixed);
  gemm_bias_kernel<float><<<dim3(64, 8), 256, 0, stream>>>(mixed, out_wt, out_b, (float*)d_out, B_ * S_, 1024, 1024);
}

// Round 8
// 287.732 us; speedup vs baseline: 1.1184x; 1.0206x over previous
//
#include <hip/hip_runtime.h>

typedef __bf16 bf16;
typedef bf16 bf16x4 __attribute__((ext_vector_type(4)));
typedef bf16 bf16x8 __attribute__((ext_vector_type(8)));
typedef float f32x4 __attribute__((ext_vector_type(4)));

#define B_ 2
#define S_ 4096
#define D_ 1024
#define QSTR 3328   // fused qkv+rq row stride

__device__ __forceinline__ void gload_lds16(const void* g, void* l) {
  __builtin_amdgcn_global_load_lds((const __attribute__((address_space(1))) void*)g,
                                   (__attribute__((address_space(3))) void*)l, 16, 0, 0);
}

// ---------------- convert: f32 -> bf16 elementwise ----------------
__global__ __launch_bounds__(256) void convert_kernel(const float* __restrict__ in,
                                                      bf16* __restrict__ out, int n4) {
  for (int i = blockIdx.x * 256 + threadIdx.x; i < n4; i += gridDim.x * 256) {
    const float4 v = ((const float4*)in)[i];
    bf16x4 o = {(bf16)v.x, (bf16)v.y, (bf16)v.z, (bf16)v.w};
    *(bf16x4*)&out[i * 4] = o;
  }
}

// ---------------- transpose+convert: in f32 [K][N] -> out bf16 [N][K] ----------------
__global__ void transpose_convert(const float* __restrict__ in, bf16* __restrict__ out,
                                  int K, int N) {
  __shared__ float tile[32][33];
  const int nb = blockIdx.x * 32;
  const int kb = blockIdx.y * 32;
  const int tx = threadIdx.x, ty = threadIdx.y;
#pragma unroll
  for (int j = 0; j < 4; j++)
    tile[ty + j * 8][tx] = in[(size_t)(kb + ty + j * 8) * N + nb + tx];
  __syncthreads();
#pragma unroll
  for (int j = 0; j < 4; j++)
    out[(size_t)(nb + ty + j * 8) * K + kb + tx] = (bf16)tile[tx][ty + j * 8];
}

// ---------------- 128-tile GEMM (balanced grids for N<=1024 shapes) ----------------
template <typename OutT>
__global__ __launch_bounds__(256) void gemm_bias_kernel(
    const bf16* __restrict__ A, const bf16* __restrict__ Bt,
    const float* __restrict__ bias, OutT* __restrict__ C,
    int M, int N, int K)
{
  __shared__ __align__(16) bf16 Al[128 * 32];
  __shared__ __align__(16) bf16 Bl[128 * 32];
  const int m0 = blockIdx.x * 128;
  const int n0 = blockIdx.y * 128;
  const int t = threadIdx.x;
  const int lane = t & 63;
  const int wave = t >> 6;
  const int wr = (wave >> 1) * 64;
  const int wc = (wave & 1) * 64;
  const int r16 = lane & 15;
  const int kg = lane >> 4;

  f32x4 acc[4][4];
#pragma unroll
  for (int i = 0; i < 4; i++)
#pragma unroll
    for (int j = 0; j < 4; j++) {
      f32x4 z = {0.f, 0.f, 0.f, 0.f};
      acc[i][j] = z;
    }

  for (int k0 = 0; k0 < K; k0 += 32) {
    __syncthreads();
#pragma unroll
    for (int i = 0; i < 2; i++) {
      const int o = i * 4096 + wave * 1024 + lane * 16;
      const int r = o >> 6;
      const int cb = o & 63;
      gload_lds16((const char*)(A + (size_t)(m0 + r) * K + k0) + cb,
                  (char*)Al + i * 4096 + wave * 1024);
      gload_lds16((const char*)(Bt + (size_t)(n0 + r) * K + k0) + cb,
                  (char*)Bl + i * 4096 + wave * 1024);
    }
    __syncthreads();
    bf16x8 a[4], b[4];
#pragma unroll
    for (int i = 0; i < 4; i++)
      a[i] = *(const bf16x8*)&Al[(wr + i * 16 + r16) * 32 + kg * 8];
#pragma unroll
    for (int i = 0; i < 4; i++)
      b[i] = *(const bf16x8*)&Bl[(wc + i * 16 + r16) * 32 + kg * 8];
#pragma unroll
    for (int i = 0; i < 4; i++)
#pragma unroll
      for (int j = 0; j < 4; j++)
        acc[i][j] = __builtin_amdgcn_mfma_f32_16x16x32_bf16(a[i], b[j], acc[i][j], 0, 0, 0);
  }

  float bs[4];
#pragma unroll
  for (int j = 0; j < 4; j++) bs[j] = bias[n0 + wc + j * 16 + r16];
#pragma unroll
  for (int i = 0; i < 4; i++)
#pragma unroll
    for (int j = 0; j < 4; j++)
#pragma unroll
      for (int r = 0; r < 4; r++) {
        const int row = m0 + wr + i * 16 + kg * 4 + r;
        const int col = n0 + wc + j * 16 + r16;
        C[(size_t)row * N + col] = (OutT)(acc[i][j][r] + bs[j]);
      }
}

// ---------------- 256x256 8-phase GEMM (frozen from round 7) ----------------
template <typename OutT>
__global__ __launch_bounds__(512, 1) void gemm8_kernel(
    const bf16* __restrict__ A, const bf16* __restrict__ Bt,
    const float* __restrict__ bias, OutT* __restrict__ C,
    int M, int N, int K)
{
  __shared__ __align__(16) bf16 Al[2][256 * 64];
  __shared__ __align__(16) bf16 Bl[2][256 * 64];

  const int nbx = gridDim.x;
  const int nwg = nbx * gridDim.y;
  int bid = blockIdx.y * nbx + blockIdx.x;
  bid = (bid & 7) * (nwg >> 3) + (bid >> 3);   // XCD swizzle (nwg % 8 == 0)
  const int m0 = (bid % nbx) * 256;
  const int n0 = (bid / nbx) * 256;

  const int t = threadIdx.x;
  const int lane = t & 63;
  const int w = t >> 6;
  const int wm = w >> 2;
  const int wn = w & 3;
  const int l15 = lane & 15;
  const int kg = lane >> 4;

  const int srow = t >> 3;
  const int schunk = (t & 7) ^ (srow & 7);
  const bf16* Aaddr = A + (size_t)(m0 + srow) * K + schunk * 8;
  const bf16* Baddr = Bt + (size_t)(n0 + srow) * K + schunk * 8;

  const int NT = K >> 6;
  const int NITER = NT >> 1;

  const int arow = wm * 128 + l15;
  const int brow = wn * 64 + l15;
  const int c0 = (kg ^ (l15 & 7)) * 16;
  const int c1 = ((4 + kg) ^ (l15 & 7)) * 16;

  f32x4 acc[8][4];
#pragma unroll
  for (int i = 0; i < 8; i++)
#pragma unroll
    for (int j = 0; j < 4; j++) { f32x4 z = {0, 0, 0, 0}; acc[i][j] = z; }

#define STG_A(buf, q, kt) gload_lds16(Aaddr + (size_t)(q) * 64 * K + (kt) * 64, \
                                      (char*)&Al[buf][0] + (q) * 8192 + w * 1024)
#define STG_B(buf, q, kt) gload_lds16(Baddr + (size_t)(q) * 64 * K + (kt) * 64, \
                                      (char*)&Bl[buf][0] + (q) * 8192 + w * 1024)
#define RD_A(buf, aq) \
  _Pragma("unroll") for (int ii = 0; ii < 4; ii++) { \
    const char* p_ = (const char*)&Al[buf][0] + (size_t)(arow + (aq) * 64 + ii * 16) * 128; \
    af[ii][0] = *(const bf16x8*)(p_ + c0); \
    af[ii][1] = *(const bf16x8*)(p_ + c1); }
#define RD_B(buf) \
  _Pragma("unroll") for (int jj = 0; jj < 4; jj++) { \
    const char* p_ = (const char*)&Bl[buf][0] + (size_t)(brow + jj * 16) * 128; \
    bfr[jj][0] = *(const bf16x8*)(p_ + c0); \
    bfr[jj][1] = *(const bf16x8*)(p_ + c1); }
#define MM(iofs, j0) \
  _Pragma("unroll") for (int ii = 0; ii < 4; ii++) \
  _Pragma("unroll") for (int jj = (j0); jj < (j0) + 2; jj++) { \
    acc[(iofs) + ii][jj] = __builtin_amdgcn_mfma_f32_16x16x32_bf16(af[ii][0], bfr[jj][0], acc[(iofs) + ii][jj], 0, 0, 0); \
    acc[(iofs) + ii][jj] = __builtin_amdgcn_mfma_f32_16x16x32_bf16(af[ii][1], bfr[jj][1], acc[(iofs) + ii][jj], 0, 0, 0); }
#define BARX __builtin_amdgcn_s_barrier()
#define LGKM0 do { asm volatile("s_waitcnt lgkmcnt(0)" ::: "memory"); \
                   __builtin_amdgcn_sched_barrier(0); } while (0)
#define PRI1 __builtin_amdgcn_s_setprio(1)
#define PRI0 __builtin_amdgcn_s_setprio(0)

#pragma unroll
  for (int q = 0; q < 4; q++) { STG_B(0, q, 0); }
#pragma unroll
  for (int q = 0; q < 4; q++) { STG_A(0, q, 0); }
#pragma unroll
  for (int q = 0; q < 4; q++) { STG_B(1, q, 1); }
#pragma unroll
  for (int q = 0; q < 4; q++) { STG_A(1, q, 1); }
  asm volatile("s_waitcnt vmcnt(8)" ::: "memory");
  BARX;

  bf16x8 af[4][2], bfr[4][2];

  for (int it = 0; it < NITER; it++) {
    const int kt0 = 2 * it;
    const bool st = (it + 1) < NITER;

    RD_A(0, 0); RD_B(0);
    BARX; LGKM0; PRI1; MM(0, 0); PRI0; BARX;
    if (st) { STG_B(0, 0, kt0 + 2); STG_B(0, 1, kt0 + 2); }
    PRI1; MM(0, 2); PRI0; BARX;
    RD_A(0, 1);
    if (st) { STG_B(0, 2, kt0 + 2); STG_B(0, 3, kt0 + 2); }
    BARX; LGKM0; PRI1; MM(4, 0); PRI0; BARX;
    if (st) { STG_A(0, 0, kt0 + 2); STG_A(0, 2, kt0 + 2); }
    PRI1; MM(4, 2); PRI0;
    asm volatile("s_waitcnt vmcnt(6)" ::: "memory");
    BARX;

    RD_A(1, 0); RD_B(1);
    if (st) { STG_A(0, 1, kt0 + 2); STG_A(0, 3, kt0 + 2); }
    BARX; LGKM0; PRI1; MM(0, 0); PRI0; BARX;
    if (st) { STG_B(1, 0, kt0 + 3); STG_B(1, 1, kt0 + 3); }
    PRI1; MM(0, 2); PRI0; BARX;
    RD_A(1, 1);
    if (st) { STG_B(1, 2, kt0 + 3); STG_B(1, 3, kt0 + 3); }
    BARX; LGKM0; PRI1; MM(4, 0); PRI0; BARX;
    if (st) { STG_A(1, 0, kt0 + 3); STG_A(1, 1, kt0 + 3);
              STG_A(1, 2, kt0 + 3); STG_A(1, 3, kt0 + 3); }
    PRI1; MM(4, 2); PRI0;
    asm volatile("s_waitcnt vmcnt(8)" ::: "memory");
    BARX;
  }

#undef STG_A
#undef STG_B
#undef RD_A
#undef RD_B
#undef MM
#undef BARX
#undef LGKM0
#undef PRI1
#undef PRI0

  float bs[4];
#pragma unroll
  for (int j = 0; j < 4; j++) bs[j] = bias[n0 + wn * 64 + j * 16 + l15];
#pragma unroll
  for (int i = 0; i < 8; i++)
#pragma unroll
    for (int j = 0; j < 4; j++)
#pragma unroll
      for (int rr = 0; rr < 4; rr++) {
        const int row = m0 + wm * 128 + i * 16 + kg * 4 + rr;
        const int col = n0 + wn * 64 + j * 16 + l15;
        C[(size_t)row * N + col] = (OutT)(acc[i][j][rr] + bs[j]);
      }
}

// ---------------- pooling (reads bf16 xb) ----------------
__global__ __launch_bounds__(256) void pool_kernel(const bf16* __restrict__ xb,
                                                   bf16* __restrict__ pooled) {
  const int blk = blockIdx.x;
  const int b = blk >> 6, lt = blk & 63;
  const int t = threadIdx.x;
  for (int d = t; d < D_; d += 256) {
    const bf16* p = xb + ((size_t)b * S_ + lt * 64) * D_ + d;
    float sum = 0.f;
#pragma unroll
    for (int c = 0; c < 64; c++) sum += (float)p[(size_t)c * D_];
    pooled[(size_t)blk * D_ + d] = (bf16)(sum * 0.015625f);
  }
}

// ---------------- latent attention (rq read from fused qkvrb) ----------------
__global__ __launch_bounds__(256) void latent_attn_kernel(
    const bf16* __restrict__ qkvrb, const bf16* __restrict__ rkvb,
    bf16* __restrict__ latout)
{
  __shared__ float rq_s[256];
  __shared__ float attn_s[4][64];
  const int blk = blockIdx.x;
  const int b = blk >> 12, s = blk & 4095;
  const int t = threadIdx.x;
  const int h = t >> 6, l = t & 63;
  const int cid = s >> 6;
  rq_s[t] = (float)qkvrb[((size_t)b * S_ + s) * QSTR + 3072 + t];
  __syncthreads();
  float val = -1e30f;
  if (l < cid) {
    const bf16* kr = rkvb + (size_t)(b * 64 + l) * 512 + h * 64;
    float sum = 0.f;
#pragma unroll
    for (int c = 0; c < 8; c++) {
      bf16x8 kv = *(const bf16x8*)(kr + c * 8);
#pragma unroll
      for (int j = 0; j < 8; j++) sum += rq_s[h * 64 + c * 8 + j] * (float)kv[j];
    }
    val = sum * 0.125f;
  }
  float mx = val;
#pragma unroll
  for (int off = 32; off; off >>= 1) mx = fmaxf(mx, __shfl_xor(mx, off));
  const float p = (l < cid) ? __expf(val - mx) : 0.f;
  float sm = p;
#pragma unroll
  for (int off = 32; off; off >>= 1) sm += __shfl_xor(sm, off);
  attn_s[h][l] = (sm > 0.f) ? p / sm : 0.f;
  __syncthreads();
  float o = 0.f;
  const bf16* vb = rkvb + (size_t)b * 64 * 512 + 256 + h * 64 + l;
  for (int lat = 0; lat < cid; lat++) o += attn_s[h][lat] * (float)vb[(size_t)lat * 512];
  latout[((size_t)b * S_ + s) * 256 + h * 64 + l] = (bf16)o;
}

// ---------------- local windowed attention, MFMA v2 ----------------
// LDS 36KB (P aliased into Kl), vectorized V-transpose (ds_write_b64),
// reg-prefetch of tile 2 K/V during tile 1 compute.
__global__ __launch_bounds__(256) void local_attn_mfma(
    const bf16* __restrict__ qkv, bf16* __restrict__ localb)
{
  __shared__ __align__(16) bf16 Kl[128 * 72];   // rows [32w,32w+16) host wave w's P after QK
  __shared__ __align__(16) bf16 Vt[64 * 136];

  const int q0 = blockIdx.x * 128;
  const int h  = blockIdx.y;
  const int b  = blockIdx.z;
  const int t  = threadIdx.x;
  const int w  = t >> 6;
  const int l  = t & 63;
  const int g  = l >> 4;
  const int l15 = l & 15;

  const bf16* qbase = qkv + (size_t)b * S_ * QSTR + h * 64;
  const bf16* kbase = qbase + 1024;
  const bf16* vbase = qbase + 2048;

  bf16* PlW = &Kl[w * 32 * 72];   // per-wave P tile [16][136] (2176 <= 2304 elems)

  const int kq = (t & 31) * 4;    // V staging: 4 k-tokens
  const int dh = (t >> 5) * 8;    // 8 d values

  bf16x8 qf[2][2];
#pragma unroll
  for (int qg = 0; qg < 2; qg++)
#pragma unroll
    for (int db = 0; db < 2; db++)
      qf[qg][db] = *(const bf16x8*)(qbase + (size_t)(q0 + w * 32 + qg * 16 + l15) * QSTR + db * 32 + g * 8);

  float m_[2][4], l_[2][4];
  f32x4 accO[2][4];
#pragma unroll
  for (int qg = 0; qg < 2; qg++) {
#pragma unroll
    for (int r = 0; r < 4; r++) { m_[qg][r] = -1e30f; l_[qg][r] = 0.f; }
#pragma unroll
    for (int dt = 0; dt < 4; dt++) { f32x4 z = {0,0,0,0}; accO[qg][dt] = z; }
  }

  const int tstart = (q0 == 0) ? 1 : 0;

  // prologue: load first tile K/V into regs
  bf16x8 kreg[4], vreg[4];
  {
    const int base = q0 - 128 + tstart * 128;
#pragma unroll
    for (int i = 0; i < 4; i++) {
      const int c = i * 256 + t;
      const int kk = c >> 3, dc = c & 7;
      kreg[i] = *(const bf16x8*)(kbase + (size_t)(base + kk) * QSTR + dc * 8);
    }
#pragma unroll
    for (int i = 0; i < 4; i++)
      vreg[i] = *(const bf16x8*)(vbase + (size_t)(base + kq + i) * QSTR + dh);
  }

  for (int tile = tstart; tile < 2; tile++) {
    __syncthreads();   // prev tile's LDS reads fully done
    // write staged regs -> LDS (K vectorized b128; V transposed via b64 packs)
#pragma unroll
    for (int i = 0; i < 4; i++) {
      const int c = i * 256 + t;
      const int kk = c >> 3, dc = c & 7;
      *(bf16x8*)&Kl[kk * 72 + dc * 8] = kreg[i];
    }
#pragma unroll
    for (int j = 0; j < 8; j++) {
      bf16x4 wv = {vreg[0][j], vreg[1][j], vreg[2][j], vreg[3][j]};
      *(bf16x4*)&Vt[(dh + j) * 136 + kq] = wv;
    }
    __syncthreads();
    // prefetch next tile into regs (hides HBM latency under compute below)
    if (tile == 0) {
#pragma unroll
      for (int i = 0; i < 4; i++) {
        const int c = i * 256 + t;
        const int kk = c >> 3, dc = c & 7;
        kreg[i] = *(const bf16x8*)(kbase + (size_t)(q0 + kk) * QSTR + dc * 8);
      }
#pragma unroll
      for (int i = 0; i < 4; i++)
        vreg[i] = *(const bf16x8*)(vbase + (size_t)(q0 + kq + i) * QSTR + dh);
    }

    const int kt_lo = (tile == 0) ? 2 * w : 0;
    const int kt_hi = (tile == 0) ? 8 : 2 * w + 2;
    const int nkt = kt_hi - kt_lo;

    f32x4 s[2][8];
#pragma unroll
    for (int qg = 0; qg < 2; qg++)
#pragma unroll
      for (int kk = 0; kk < 8; kk++) { f32x4 z = {0,0,0,0}; s[qg][kk] = z; }

#pragma unroll
    for (int kk = 0; kk < 8; kk++) {
      if (kk >= nkt) continue;
      const int kt = kt_lo + kk;
      const bf16x8 kf0 = *(const bf16x8*)&Kl[(kt * 16 + l15) * 72 + g * 8];
      const bf16x8 kf1 = *(const bf16x8*)&Kl[(kt * 16 + l15) * 72 + 32 + g * 8];
      s[0][kk] = __builtin_amdgcn_mfma_f32_16x16x32_bf16(qf[0][0], kf0, s[0][kk], 0, 0, 0);
      s[0][kk] = __builtin_amdgcn_mfma_f32_16x16x32_bf16(qf[0][1], kf1, s[0][kk], 0, 0, 0);
      s[1][kk] = __builtin_amdgcn_mfma_f32_16x16x32_bf16(qf[1][0], kf0, s[1][kk], 0, 0, 0);
      s[1][kk] = __builtin_amdgcn_mfma_f32_16x16x32_bf16(qf[1][1], kf1, s[1][kk], 0, 0, 0);
    }
    // all waves' Kl reads must retire before P overwrites Kl rows
    asm volatile("s_waitcnt lgkmcnt(0)" ::: "memory");
    __builtin_amdgcn_s_barrier();

#pragma unroll
    for (int qg = 0; qg < 2; qg++) {
#pragma unroll
      for (int kk = 0; kk < 8; kk++) {
        if (kk >= nkt) continue;
        const int kr = (kt_lo + kk) * 16 + l15;
#pragma unroll
        for (int r = 0; r < 4; r++) {
          const int qr = w * 32 + qg * 16 + g * 4 + r;
          const bool ok = (tile == 0) ? (kr >= qr) : (kr < qr);
          s[qg][kk][r] = ok ? s[qg][kk][r] * 0.125f : -1e9f;
        }
      }
      float corr[4];
#pragma unroll
      for (int r = 0; r < 4; r++) {
        float v = -1e30f;
#pragma unroll
        for (int kk = 0; kk < 8; kk++) { if (kk >= nkt) continue; v = fmaxf(v, s[qg][kk][r]); }
        v = fmaxf(v, __shfl_xor(v, 1));
        v = fmaxf(v, __shfl_xor(v, 2));
        v = fmaxf(v, __shfl_xor(v, 4));
        v = fmaxf(v, __shfl_xor(v, 8));
        const float mn = fmaxf(m_[qg][r], v);
        corr[r] = __expf(m_[qg][r] - mn);
        m_[qg][r] = mn;
      }
      float rs[4] = {0.f, 0.f, 0.f, 0.f};
#pragma unroll
      for (int kk = 0; kk < 8; kk++) {
        if (kk >= nkt) continue;
        const int kt = kt_lo + kk;
#pragma unroll
        for (int r = 0; r < 4; r++) {
          const float sv = s[qg][kk][r];
          const float p = (sv > -5e8f) ? __expf(sv - m_[qg][r]) : 0.f;
          rs[r] += p;
          PlW[(g * 4 + r) * 136 + kt * 16 + l15] = (bf16)p;
        }
      }
#pragma unroll
      for (int r = 0; r < 4; r++) {
        float v = rs[r];
        v += __shfl_xor(v, 1); v += __shfl_xor(v, 2);
        v += __shfl_xor(v, 4); v += __shfl_xor(v, 8);
        l_[qg][r] = l_[qg][r] * corr[r] + v;
#pragma unroll
        for (int dt = 0; dt < 4; dt++) accO[qg][dt][r] *= corr[r];
      }
      asm volatile("s_waitcnt lgkmcnt(0)" ::: "memory");
      __builtin_amdgcn_sched_barrier(0);
      const int kc_lo = (tile == 0) ? w : 0;
      const int kc_hi = (tile == 0) ? 4 : w + 1;
#pragma unroll
      for (int kc = 0; kc < 4; kc++) {
        if (kc < kc_lo || kc >= kc_hi) continue;
        const bf16x8 pa = *(const bf16x8*)&PlW[l15 * 136 + kc * 32 + g * 8];
#pragma unroll
        for (int dt = 0; dt < 4; dt++) {
          const bf16x8 vf = *(const bf16x8*)&Vt[(dt * 16 + l15) * 136 + kc * 32 + g * 8];
          accO[qg][dt] = __builtin_amdgcn_mfma_f32_16x16x32_bf16(pa, vf, accO[qg][dt], 0, 0, 0);
        }
      }
    }
  }

  bf16* outp = localb + ((size_t)b * S_ + q0 + w * 32) * 1024 + h * 64;
#pragma unroll
  for (int qg = 0; qg < 2; qg++)
#pragma unroll
    for (int r = 0; r < 4; r++) {
      const float inv = (l_[qg][r] > 0.f) ? 1.f / l_[qg][r] : 0.f;
#pragma unroll
      for (int dt = 0; dt < 4; dt++)
        outp[(size_t)(qg * 16 + g * 4 + r) * 1024 + dt * 16 + l15] = (bf16)(accO[qg][dt][r] * inv);
    }
}

// ---------------- gate + mix ----------------
__global__ __launch_bounds__(1024) void gate_mix_kernel(
    const bf16* __restrict__ localb, const bf16* __restrict__ remote,
    const float* __restrict__ glw, const float* __restrict__ grw,
    bf16* __restrict__ mixed)
{
  const int blk = blockIdx.x;
  const int b = blk >> 12, s = blk & 4095;
  const int t = threadIdx.x;
  const int d = t & 63;
  const size_t idx = ((size_t)b * S_ + s) * 1024 + t;
  const float lf = (float)localb[idx], rf = (float)remote[idx];
  float part = lf * glw[d] + rf * grw[d];
#pragma unroll
  for (int off = 32; off; off >>= 1) part += __shfl_xor(part, off);
  const float g = 1.f / (1.f + __expf(-part));
  mixed[idx] = (bf16)(g * lf + (1.f - g) * rf);
}

// ---------------- launch ----------------
extern "C" void kernel_launch(void* const* d_in, const int* in_sizes, int n_in,
                              void* d_out, int out_size, void* d_ws, size_t ws_size,
                              hipStream_t stream)
{
  const float* x      = (const float*)d_in[0];
  const float* qkv_w  = (const float*)d_in[1];
  const float* qkv_b  = (const float*)d_in[2];
  const float* rq_w   = (const float*)d_in[3];
  const float* rq_b   = (const float*)d_in[4];
  const float* rkv_w  = (const float*)d_in[5];
  const float* rkv_b  = (const float*)d_in[6];
  const float* rout_w = (const float*)d_in[7];
  const float* rout_b = (const float*)d_in[8];
  const float* out_w  = (const float*)d_in[9];
  const float* out_b  = (const float*)d_in[10];
  const float* gl_w   = (const float*)d_in[11];
  const float* gr_w   = (const float*)d_in[12];

  char* w = (char*)d_ws;
  bf16* qkvr_wt = (bf16*)w; w += (size_t)QSTR * 1024 * 2;
  bf16* rkv_wt  = (bf16*)w; w += (size_t)512 * 1024 * 2;
  bf16* rout_wt = (bf16*)w; w += (size_t)1024 * 256 * 2;
  bf16* out_wt  = (bf16*)w; w += (size_t)1024 * 1024 * 2;
  float* qkvr_b = (float*)w; w += (size_t)QSTR * 4;
  bf16* xb      = (bf16*)w; w += (size_t)B_ * S_ * 1024 * 2;
  bf16* qkvrb   = (bf16*)w; w += (size_t)B_ * S_ * QSTR * 2;
  bf16* pooled  = (bf16*)w; w += (size_t)B_ * 64 * 1024 * 2;
  bf16* rkvb    = (bf16*)w; w += (size_t)B_ * 64 * 512 * 2;
  bf16* latout  = (bf16*)w; w += (size_t)B_ * S_ * 256 * 2;
  bf16* remote  = (bf16*)w; w += (size_t)B_ * S_ * 1024 * 2;
  bf16* localb  = (bf16*)w; w += (size_t)B_ * S_ * 1024 * 2;
  bf16* mixed   = qkvrb;  // reuse: qkvrb dead after local_attn + latent

  hipMemcpyAsync(qkvr_b, qkv_b, 3072 * sizeof(float), hipMemcpyDeviceToDevice, stream);
  hipMemcpyAsync(qkvr_b + 3072, rq_b, 256 * sizeof(float), hipMemcpyDeviceToDevice, stream);

  const dim3 tb(32, 8);
  transpose_convert<<<dim3(96, 32), tb, 0, stream>>>(qkv_w, qkvr_wt, 1024, 3072);
  transpose_convert<<<dim3(8, 32),  tb, 0, stream>>>(rq_w, qkvr_wt + (size_t)3072 * 1024, 1024, 256);
  transpose_convert<<<dim3(16, 32), tb, 0, stream>>>(rkv_w, rkv_wt, 1024, 512);
  transpose_convert<<<dim3(32, 8),  tb, 0, stream>>>(rout_w, rout_wt, 256, 1024);
  transpose_convert<<<dim3(32, 32), tb, 0, stream>>>(out_w, out_wt, 1024, 1024);
  convert_kernel<<<dim3(2048), 256, 0, stream>>>(x, xb, B_ * S_ * 1024 / 4);

  gemm8_kernel<bf16><<<dim3(32, 13), 512, 0, stream>>>(xb, qkvr_wt, qkvr_b, qkvrb, B_ * S_, QSTR, 1024);
  pool_kernel<<<dim3(B_ * 64), 256, 0, stream>>>(xb, pooled);
  gemm_bias_kernel<bf16><<<dim3(1, 4), 256, 0, stream>>>(pooled, rkv_wt, rkv_b, rkvb, B_ * 64, 512, 1024);
  latent_attn_kernel<<<dim3(B_ * S_), 256, 0, stream>>>(qkvrb, rkvb, latout);
  gemm_bias_kernel<bf16><<<dim3(64, 8), 256, 0, stream>>>(latout, rout_wt, rout_b, remote, B_ * S_, 1024, 256);
  local_attn_mfma<<<dim3(S_ / 128, 16, B_), 256, 0, stream>>>(qkvrb, localb);
  gate_mix_kernel<<<dim3(B_ * S_), 1024, 0, stream>>>(localb, remote, gl_w, gr_w, mixed);
  gemm_bias_kernel<float><<<dim3(64, 8), 256, 0, stream>>>(mixed, out_wt, out_b, (float*)d_out, B_ * S_, 1024, 1024);
}

// Round 9
// 267.603 us; speedup vs baseline: 1.2025x; 1.0752x over previous
//
#include <hip/hip_runtime.h>

typedef __bf16 bf16;
typedef bf16 bf16x4 __attribute__((ext_vector_type(4)));
typedef bf16 bf16x8 __attribute__((ext_vector_type(8)));
typedef float f32x4 __attribute__((ext_vector_type(4)));

#define B_ 2
#define S_ 4096
#define D_ 1024
#define QSTR 3328   // fused qkv+rq row stride

__device__ __forceinline__ void gload_lds16(const void* g, void* l) {
  __builtin_amdgcn_global_load_lds((const __attribute__((address_space(1))) void*)g,
                                   (__attribute__((address_space(3))) void*)l, 16, 0, 0);
}

// ---------------- fused prep: 5 weight transposes + x->bf16 convert ----------------
__device__ __forceinline__ void transpose_block(
    const float* __restrict__ in, bf16* __restrict__ out, int K, int N,
    int bx, int by, float (*tile)[33], int tx, int ty)
{
  const int nb = bx * 32, kb = by * 32;
#pragma unroll
  for (int j = 0; j < 4; j++)
    tile[ty + j * 8][tx] = in[(size_t)(kb + ty + j * 8) * N + nb + tx];
  __syncthreads();
#pragma unroll
  for (int j = 0; j < 4; j++)
    out[(size_t)(nb + ty + j * 8) * K + kb + tx] = (bf16)tile[tx][ty + j * 8];
}

__global__ __launch_bounds__(256) void prep_kernel(
    const float* __restrict__ qkv_w, const float* __restrict__ rq_w,
    const float* __restrict__ rkv_w, const float* __restrict__ rout_w,
    const float* __restrict__ out_w, const float* __restrict__ x,
    bf16* __restrict__ qkvr_wt, bf16* __restrict__ rkv_wt,
    bf16* __restrict__ rout_wt, bf16* __restrict__ out_wt,
    bf16* __restrict__ xb)
{
  __shared__ float tile[32][33];
  const int t = threadIdx.x;
  const int tx = t & 31, ty = t >> 5;
  int bid = blockIdx.x;
  if (bid < 3072) {        // qkv_w [1024][3072] -> qkvr_wt[0:3072][1024]
    transpose_block(qkv_w, qkvr_wt, 1024, 3072, bid % 96, bid / 96, tile, tx, ty);
    return;
  }
  bid -= 3072;
  if (bid < 256) {         // rq_w [1024][256] -> qkvr_wt[3072:3328][1024]
    transpose_block(rq_w, qkvr_wt + (size_t)3072 * 1024, 1024, 256, bid % 8, bid / 8, tile, tx, ty);
    return;
  }
  bid -= 256;
  if (bid < 512) {         // rkv_w [1024][512] -> rkv_wt[512][1024]
    transpose_block(rkv_w, rkv_wt, 1024, 512, bid % 16, bid / 16, tile, tx, ty);
    return;
  }
  bid -= 512;
  if (bid < 256) {         // rout_w [256][1024] -> rout_wt[1024][256]
    transpose_block(rout_w, rout_wt, 256, 1024, bid % 32, bid / 32, tile, tx, ty);
    return;
  }
  bid -= 256;
  if (bid < 1024) {        // out_w [1024][1024] -> out_wt[1024][1024]
    transpose_block(out_w, out_wt, 1024, 1024, bid % 32, bid / 32, tile, tx, ty);
    return;
  }
  bid -= 1024;             // convert x -> xb over 2048 virtual blocks
  const int n4 = B_ * S_ * 1024 / 4;
  for (int i = bid * 256 + t; i < n4; i += 2048 * 256) {
    const float4 v = ((const float4*)x)[i];
    bf16x4 o = {(bf16)v.x, (bf16)v.y, (bf16)v.z, (bf16)v.w};
    *(bf16x4*)&xb[i * 4] = o;
  }
}

// ---------------- 128-tile GEMM (balanced grids for N<=1024 shapes) ----------------
template <typename OutT>
__global__ __launch_bounds__(256) void gemm_bias_kernel(
    const bf16* __restrict__ A, const bf16* __restrict__ Bt,
    const float* __restrict__ bias, OutT* __restrict__ C,
    int M, int N, int K)
{
  __shared__ __align__(16) bf16 Al[128 * 32];
  __shared__ __align__(16) bf16 Bl[128 * 32];
  const int m0 = blockIdx.x * 128;
  const int n0 = blockIdx.y * 128;
  const int t = threadIdx.x;
  const int lane = t & 63;
  const int wave = t >> 6;
  const int wr = (wave >> 1) * 64;
  const int wc = (wave & 1) * 64;
  const int r16 = lane & 15;
  const int kg = lane >> 4;

  f32x4 acc[4][4];
#pragma unroll
  for (int i = 0; i < 4; i++)
#pragma unroll
    for (int j = 0; j < 4; j++) {
      f32x4 z = {0.f, 0.f, 0.f, 0.f};
      acc[i][j] = z;
    }

  for (int k0 = 0; k0 < K; k0 += 32) {
    __syncthreads();
#pragma unroll
    for (int i = 0; i < 2; i++) {
      const int o = i * 4096 + wave * 1024 + lane * 16;
      const int r = o >> 6;
      const int cb = o & 63;
      gload_lds16((const char*)(A + (size_t)(m0 + r) * K + k0) + cb,
                  (char*)Al + i * 4096 + wave * 1024);
      gload_lds16((const char*)(Bt + (size_t)(n0 + r) * K + k0) + cb,
                  (char*)Bl + i * 4096 + wave * 1024);
    }
    __syncthreads();
    bf16x8 a[4], b[4];
#pragma unroll
    for (int i = 0; i < 4; i++)
      a[i] = *(const bf16x8*)&Al[(wr + i * 16 + r16) * 32 + kg * 8];
#pragma unroll
    for (int i = 0; i < 4; i++)
      b[i] = *(const bf16x8*)&Bl[(wc + i * 16 + r16) * 32 + kg * 8];
#pragma unroll
    for (int i = 0; i < 4; i++)
#pragma unroll
      for (int j = 0; j < 4; j++)
        acc[i][j] = __builtin_amdgcn_mfma_f32_16x16x32_bf16(a[i], b[j], acc[i][j], 0, 0, 0);
  }

  float bs[4];
#pragma unroll
  for (int j = 0; j < 4; j++) bs[j] = bias[n0 + wc + j * 16 + r16];
#pragma unroll
  for (int i = 0; i < 4; i++)
#pragma unroll
    for (int j = 0; j < 4; j++)
#pragma unroll
      for (int r = 0; r < 4; r++) {
        const int row = m0 + wr + i * 16 + kg * 4 + r;
        const int col = n0 + wc + j * 16 + r16;
        C[(size_t)row * N + col] = (OutT)(acc[i][j][r] + bs[j]);
      }
}

// ---------------- 256x256 8-phase GEMM (frozen) ----------------
template <typename OutT>
__global__ __launch_bounds__(512, 1) void gemm8_kernel(
    const bf16* __restrict__ A, const bf16* __restrict__ Bt,
    const float* __restrict__ bias, OutT* __restrict__ C,
    int M, int N, int K)
{
  __shared__ __align__(16) bf16 Al[2][256 * 64];
  __shared__ __align__(16) bf16 Bl[2][256 * 64];

  const int nbx = gridDim.x;
  const int nwg = nbx * gridDim.y;
  int bid = blockIdx.y * nbx + blockIdx.x;
  bid = (bid & 7) * (nwg >> 3) + (bid >> 3);   // XCD swizzle (nwg % 8 == 0)
  const int m0 = (bid % nbx) * 256;
  const int n0 = (bid / nbx) * 256;

  const int t = threadIdx.x;
  const int lane = t & 63;
  const int w = t >> 6;
  const int wm = w >> 2;
  const int wn = w & 3;
  const int l15 = lane & 15;
  const int kg = lane >> 4;

  const int srow = t >> 3;
  const int schunk = (t & 7) ^ (srow & 7);
  const bf16* Aaddr = A + (size_t)(m0 + srow) * K + schunk * 8;
  const bf16* Baddr = Bt + (size_t)(n0 + srow) * K + schunk * 8;

  const int NT = K >> 6;
  const int NITER = NT >> 1;

  const int arow = wm * 128 + l15;
  const int brow = wn * 64 + l15;
  const int c0 = (kg ^ (l15 & 7)) * 16;
  const int c1 = ((4 + kg) ^ (l15 & 7)) * 16;

  f32x4 acc[8][4];
#pragma unroll
  for (int i = 0; i < 8; i++)
#pragma unroll
    for (int j = 0; j < 4; j++) { f32x4 z = {0, 0, 0, 0}; acc[i][j] = z; }

#define STG_A(buf, q, kt) gload_lds16(Aaddr + (size_t)(q) * 64 * K + (kt) * 64, \
                                      (char*)&Al[buf][0] + (q) * 8192 + w * 1024)
#define STG_B(buf, q, kt) gload_lds16(Baddr + (size_t)(q) * 64 * K + (kt) * 64, \
                                      (char*)&Bl[buf][0] + (q) * 8192 + w * 1024)
#define RD_A(buf, aq) \
  _Pragma("unroll") for (int ii = 0; ii < 4; ii++) { \
    const char* p_ = (const char*)&Al[buf][0] + (size_t)(arow + (aq) * 64 + ii * 16) * 128; \
    af[ii][0] = *(const bf16x8*)(p_ + c0); \
    af[ii][1] = *(const bf16x8*)(p_ + c1); }
#define RD_B(buf) \
  _Pragma("unroll") for (int jj = 0; jj < 4; jj++) { \
    const char* p_ = (const char*)&Bl[buf][0] + (size_t)(brow + jj * 16) * 128; \
    bfr[jj][0] = *(const bf16x8*)(p_ + c0); \
    bfr[jj][1] = *(const bf16x8*)(p_ + c1); }
#define MM(iofs, j0) \
  _Pragma("unroll") for (int ii = 0; ii < 4; ii++) \
  _Pragma("unroll") for (int jj = (j0); jj < (j0) + 2; jj++) { \
    acc[(iofs) + ii][jj] = __builtin_amdgcn_mfma_f32_16x16x32_bf16(af[ii][0], bfr[jj][0], acc[(iofs) + ii][jj], 0, 0, 0); \
    acc[(iofs) + ii][jj] = __builtin_amdgcn_mfma_f32_16x16x32_bf16(af[ii][1], bfr[jj][1], acc[(iofs) + ii][jj], 0, 0, 0); }
#define BARX __builtin_amdgcn_s_barrier()
#define LGKM0 do { asm volatile("s_waitcnt lgkmcnt(0)" ::: "memory"); \
                   __builtin_amdgcn_sched_barrier(0); } while (0)
#define PRI1 __builtin_amdgcn_s_setprio(1)
#define PRI0 __builtin_amdgcn_s_setprio(0)

#pragma unroll
  for (int q = 0; q < 4; q++) { STG_B(0, q, 0); }
#pragma unroll
  for (int q = 0; q < 4; q++) { STG_A(0, q, 0); }
#pragma unroll
  for (int q = 0; q < 4; q++) { STG_B(1, q, 1); }
#pragma unroll
  for (int q = 0; q < 4; q++) { STG_A(1, q, 1); }
  asm volatile("s_waitcnt vmcnt(8)" ::: "memory");
  BARX;

  bf16x8 af[4][2], bfr[4][2];

  for (int it = 0; it < NITER; it++) {
    const int kt0 = 2 * it;
    const bool st = (it + 1) < NITER;

    RD_A(0, 0); RD_B(0);
    BARX; LGKM0; PRI1; MM(0, 0); PRI0; BARX;
    if (st) { STG_B(0, 0, kt0 + 2); STG_B(0, 1, kt0 + 2); }
    PRI1; MM(0, 2); PRI0; BARX;
    RD_A(0, 1);
    if (st) { STG_B(0, 2, kt0 + 2); STG_B(0, 3, kt0 + 2); }
    BARX; LGKM0; PRI1; MM(4, 0); PRI0; BARX;
    if (st) { STG_A(0, 0, kt0 + 2); STG_A(0, 2, kt0 + 2); }
    PRI1; MM(4, 2); PRI0;
    asm volatile("s_waitcnt vmcnt(6)" ::: "memory");
    BARX;

    RD_A(1, 0); RD_B(1);
    if (st) { STG_A(0, 1, kt0 + 2); STG_A(0, 3, kt0 + 2); }
    BARX; LGKM0; PRI1; MM(0, 0); PRI0; BARX;
    if (st) { STG_B(1, 0, kt0 + 3); STG_B(1, 1, kt0 + 3); }
    PRI1; MM(0, 2); PRI0; BARX;
    RD_A(1, 1);
    if (st) { STG_B(1, 2, kt0 + 3); STG_B(1, 3, kt0 + 3); }
    BARX; LGKM0; PRI1; MM(4, 0); PRI0; BARX;
    if (st) { STG_A(1, 0, kt0 + 3); STG_A(1, 1, kt0 + 3);
              STG_A(1, 2, kt0 + 3); STG_A(1, 3, kt0 + 3); }
    PRI1; MM(4, 2); PRI0;
    asm volatile("s_waitcnt vmcnt(8)" ::: "memory");
    BARX;
  }

#undef STG_A
#undef STG_B
#undef RD_A
#undef RD_B
#undef MM
#undef BARX
#undef LGKM0
#undef PRI1
#undef PRI0

  float bs[4];
#pragma unroll
  for (int j = 0; j < 4; j++) bs[j] = bias[n0 + wn * 64 + j * 16 + l15];
#pragma unroll
  for (int i = 0; i < 8; i++)
#pragma unroll
    for (int j = 0; j < 4; j++)
#pragma unroll
      for (int rr = 0; rr < 4; rr++) {
        const int row = m0 + wm * 128 + i * 16 + kg * 4 + rr;
        const int col = n0 + wn * 64 + j * 16 + l15;
        C[(size_t)row * N + col] = (OutT)(acc[i][j][rr] + bs[j]);
      }
}

// ---------------- fused pool + rkv GEMV ----------------
// grid (128, 2), 256 thr. Block (b*64+lt, half): pooled row -> LDS (f32),
// then each thread computes one rkv output column (256 cols per half).
__global__ __launch_bounds__(256) void pool_rkv_kernel(
    const bf16* __restrict__ xb, const bf16* __restrict__ rkv_wt,
    const float* __restrict__ rkv_b, bf16* __restrict__ rkvb)
{
  __shared__ float prow[1024];
  const int blk = blockIdx.x;              // b*64 + lt
  const int b = blk >> 6, lt = blk & 63;
  const int t = threadIdx.x;

  const bf16* px = xb + ((size_t)b * S_ + lt * 64) * 1024 + t * 4;
  float s0 = 0.f, s1 = 0.f, s2 = 0.f, s3 = 0.f;
#pragma unroll
  for (int c = 0; c < 64; c++) {
    bf16x4 v = *(const bf16x4*)(px + (size_t)c * 1024);
    s0 += (float)v[0]; s1 += (float)v[1]; s2 += (float)v[2]; s3 += (float)v[3];
  }
  prow[t * 4 + 0] = s0 * 0.015625f;
  prow[t * 4 + 1] = s1 * 0.015625f;
  prow[t * 4 + 2] = s2 * 0.015625f;
  prow[t * 4 + 3] = s3 * 0.015625f;
  __syncthreads();

  const int n = blockIdx.y * 256 + t;      // output column 0..511
  const bf16* wcol = rkv_wt + (size_t)n * 1024;
  float s = rkv_b[n];
#pragma unroll 4
  for (int k = 0; k < 1024; k += 8) {
    bf16x8 wv = *(const bf16x8*)(wcol + k);
#pragma unroll
    for (int j = 0; j < 8; j++) s += prow[k + j] * (float)wv[j];
  }
  rkvb[(size_t)blk * 512 + n] = (bf16)s;
}

// ---------------- latent attention (rq read from fused qkvrb) ----------------
__global__ __launch_bounds__(256) void latent_attn_kernel(
    const bf16* __restrict__ qkvrb, const bf16* __restrict__ rkvb,
    bf16* __restrict__ latout)
{
  __shared__ float rq_s[256];
  __shared__ float attn_s[4][64];
  const int blk = blockIdx.x;
  const int b = blk >> 12, s = blk & 4095;
  const int t = threadIdx.x;
  const int h = t >> 6, l = t & 63;
  const int cid = s >> 6;
  rq_s[t] = (float)qkvrb[((size_t)b * S_ + s) * QSTR + 3072 + t];
  __syncthreads();
  float val = -1e30f;
  if (l < cid) {
    const bf16* kr = rkvb + (size_t)(b * 64 + l) * 512 + h * 64;
    float sum = 0.f;
#pragma unroll
    for (int c = 0; c < 8; c++) {
      bf16x8 kv = *(const bf16x8*)(kr + c * 8);
#pragma unroll
      for (int j = 0; j < 8; j++) sum += rq_s[h * 64 + c * 8 + j] * (float)kv[j];
    }
    val = sum * 0.125f;
  }
  float mx = val;
#pragma unroll
  for (int off = 32; off; off >>= 1) mx = fmaxf(mx, __shfl_xor(mx, off));
  const float p = (l < cid) ? __expf(val - mx) : 0.f;
  float sm = p;
#pragma unroll
  for (int off = 32; off; off >>= 1) sm += __shfl_xor(sm, off);
  attn_s[h][l] = (sm > 0.f) ? p / sm : 0.f;
  __syncthreads();
  float o = 0.f;
  const bf16* vb = rkvb + (size_t)b * 64 * 512 + 256 + h * 64 + l;
  for (int lat = 0; lat < cid; lat++) o += attn_s[h][lat] * (float)vb[(size_t)lat * 512];
  latout[((size_t)b * S_ + s) * 256 + h * 64 + l] = (bf16)o;
}

// ---------------- local windowed attention, MFMA v2 ----------------
__global__ __launch_bounds__(256) void local_attn_mfma(
    const bf16* __restrict__ qkv, bf16* __restrict__ localb)
{
  __shared__ __align__(16) bf16 Kl[128 * 72];
  __shared__ __align__(16) bf16 Vt[64 * 136];

  const int q0 = blockIdx.x * 128;
  const int h  = blockIdx.y;
  const int b  = blockIdx.z;
  const int t  = threadIdx.x;
  const int w  = t >> 6;
  const int l  = t & 63;
  const int g  = l >> 4;
  const int l15 = l & 15;

  const bf16* qbase = qkv + (size_t)b * S_ * QSTR + h * 64;
  const bf16* kbase = qbase + 1024;
  const bf16* vbase = qbase + 2048;

  bf16* PlW = &Kl[w * 32 * 72];

  const int kq = (t & 31) * 4;
  const int dh = (t >> 5) * 8;

  bf16x8 qf[2][2];
#pragma unroll
  for (int qg = 0; qg < 2; qg++)
#pragma unroll
    for (int db = 0; db < 2; db++)
      qf[qg][db] = *(const bf16x8*)(qbase + (size_t)(q0 + w * 32 + qg * 16 + l15) * QSTR + db * 32 + g * 8);

  float m_[2][4], l_[2][4];
  f32x4 accO[2][4];
#pragma unroll
  for (int qg = 0; qg < 2; qg++) {
#pragma unroll
    for (int r = 0; r < 4; r++) { m_[qg][r] = -1e30f; l_[qg][r] = 0.f; }
#pragma unroll
    for (int dt = 0; dt < 4; dt++) { f32x4 z = {0,0,0,0}; accO[qg][dt] = z; }
  }

  const int tstart = (q0 == 0) ? 1 : 0;

  bf16x8 kreg[4], vreg[4];
  {
    const int base = q0 - 128 + tstart * 128;
#pragma unroll
    for (int i = 0; i < 4; i++) {
      const int c = i * 256 + t;
      const int kk = c >> 3, dc = c & 7;
      kreg[i] = *(const bf16x8*)(kbase + (size_t)(base + kk) * QSTR + dc * 8);
    }
#pragma unroll
    for (int i = 0; i < 4; i++)
      vreg[i] = *(const bf16x8*)(vbase + (size_t)(base + kq + i) * QSTR + dh);
  }

  for (int tile = tstart; tile < 2; tile++) {
    __syncthreads();
#pragma unroll
    for (int i = 0; i < 4; i++) {
      const int c = i * 256 + t;
      const int kk = c >> 3, dc = c & 7;
      *(bf16x8*)&Kl[kk * 72 + dc * 8] = kreg[i];
    }
#pragma unroll
    for (int j = 0; j < 8; j++) {
      bf16x4 wv = {vreg[0][j], vreg[1][j], vreg[2][j], vreg[3][j]};
      *(bf16x4*)&Vt[(dh + j) * 136 + kq] = wv;
    }
    __syncthreads();
    if (tile == 0) {
#pragma unroll
      for (int i = 0; i < 4; i++) {
        const int c = i * 256 + t;
        const int kk = c >> 3, dc = c & 7;
        kreg[i] = *(const bf16x8*)(kbase + (size_t)(q0 + kk) * QSTR + dc * 8);
      }
#pragma unroll
      for (int i = 0; i < 4; i++)
        vreg[i] = *(const bf16x8*)(vbase + (size_t)(q0 + kq + i) * QSTR + dh);
    }

    const int kt_lo = (tile == 0) ? 2 * w : 0;
    const int kt_hi = (tile == 0) ? 8 : 2 * w + 2;
    const int nkt = kt_hi - kt_lo;

    f32x4 s[2][8];
#pragma unroll
    for (int qg = 0; qg < 2; qg++)
#pragma unroll
      for (int kk = 0; kk < 8; kk++) { f32x4 z = {0,0,0,0}; s[qg][kk] = z; }

#pragma unroll
    for (int kk = 0; kk < 8; kk++) {
      if (kk >= nkt) continue;
      const int kt = kt_lo + kk;
      const bf16x8 kf0 = *(const bf16x8*)&Kl[(kt * 16 + l15) * 72 + g * 8];
      const bf16x8 kf1 = *(const bf16x8*)&Kl[(kt * 16 + l15) * 72 + 32 + g * 8];
      s[0][kk] = __builtin_amdgcn_mfma_f32_16x16x32_bf16(qf[0][0], kf0, s[0][kk], 0, 0, 0);
      s[0][kk] = __builtin_amdgcn_mfma_f32_16x16x32_bf16(qf[0][1], kf1, s[0][kk], 0, 0, 0);
      s[1][kk] = __builtin_amdgcn_mfma_f32_16x16x32_bf16(qf[1][0], kf0, s[1][kk], 0, 0, 0);
      s[1][kk] = __builtin_amdgcn_mfma_f32_16x16x32_bf16(qf[1][1], kf1, s[1][kk], 0, 0, 0);
    }
    asm volatile("s_waitcnt lgkmcnt(0)" ::: "memory");
    __builtin_amdgcn_s_barrier();

#pragma unroll
    for (int qg = 0; qg < 2; qg++) {
#pragma unroll
      for (int kk = 0; kk < 8; kk++) {
        if (kk >= nkt) continue;
        const int kr = (kt_lo + kk) * 16 + l15;
#pragma unroll
        for (int r = 0; r < 4; r++) {
          const int qr = w * 32 + qg * 16 + g * 4 + r;
          const bool ok = (tile == 0) ? (kr >= qr) : (kr < qr);
          s[qg][kk][r] = ok ? s[qg][kk][r] * 0.125f : -1e9f;
        }
      }
      float corr[4];
#pragma unroll
      for (int r = 0; r < 4; r++) {
        float v = -1e30f;
#pragma unroll
        for (int kk = 0; kk < 8; kk++) { if (kk >= nkt) continue; v = fmaxf(v, s[qg][kk][r]); }
        v = fmaxf(v, __shfl_xor(v, 1));
        v = fmaxf(v, __shfl_xor(v, 2));
        v = fmaxf(v, __shfl_xor(v, 4));
        v = fmaxf(v, __shfl_xor(v, 8));
        const float mn = fmaxf(m_[qg][r], v);
        corr[r] = __expf(m_[qg][r] - mn);
        m_[qg][r] = mn;
      }
      float rs[4] = {0.f, 0.f, 0.f, 0.f};
#pragma unroll
      for (int kk = 0; kk < 8; kk++) {
        if (kk >= nkt) continue;
        const int kt = kt_lo + kk;
#pragma unroll
        for (int r = 0; r < 4; r++) {
          const float sv = s[qg][kk][r];
          const float p = (sv > -5e8f) ? __expf(sv - m_[qg][r]) : 0.f;
          rs[r] += p;
          PlW[(g * 4 + r) * 136 + kt * 16 + l15] = (bf16)p;
        }
      }
#pragma unroll
      for (int r = 0; r < 4; r++) {
        float v = rs[r];
        v += __shfl_xor(v, 1); v += __shfl_xor(v, 2);
        v += __shfl_xor(v, 4); v += __shfl_xor(v, 8);
        l_[qg][r] = l_[qg][r] * corr[r] + v;
#pragma unroll
        for (int dt = 0; dt < 4; dt++) accO[qg][dt][r] *= corr[r];
      }
      asm volatile("s_waitcnt lgkmcnt(0)" ::: "memory");
      __builtin_amdgcn_sched_barrier(0);
      const int kc_lo = (tile == 0) ? w : 0;
      const int kc_hi = (tile == 0) ? 4 : w + 1;
#pragma unroll
      for (int kc = 0; kc < 4; kc++) {
        if (kc < kc_lo || kc >= kc_hi) continue;
        const bf16x8 pa = *(const bf16x8*)&PlW[l15 * 136 + kc * 32 + g * 8];
#pragma unroll
        for (int dt = 0; dt < 4; dt++) {
          const bf16x8 vf = *(const bf16x8*)&Vt[(dt * 16 + l15) * 136 + kc * 32 + g * 8];
          accO[qg][dt] = __builtin_amdgcn_mfma_f32_16x16x32_bf16(pa, vf, accO[qg][dt], 0, 0, 0);
        }
      }
    }
  }

  bf16* outp = localb + ((size_t)b * S_ + q0 + w * 32) * 1024 + h * 64;
#pragma unroll
  for (int qg = 0; qg < 2; qg++)
#pragma unroll
    for (int r = 0; r < 4; r++) {
      const float inv = (l_[qg][r] > 0.f) ? 1.f / l_[qg][r] : 0.f;
#pragma unroll
      for (int dt = 0; dt < 4; dt++)
        outp[(size_t)(qg * 16 + g * 4 + r) * 1024 + dt * 16 + l15] = (bf16)(accO[qg][dt][r] * inv);
    }
}

// ---------------- gate + mix ----------------
__global__ __launch_bounds__(1024) void gate_mix_kernel(
    const bf16* __restrict__ localb, const bf16* __restrict__ remote,
    const float* __restrict__ glw, const float* __restrict__ grw,
    bf16* __restrict__ mixed)
{
  const int blk = blockIdx.x;
  const int b = blk >> 12, s = blk & 4095;
  const int t = threadIdx.x;
  const int d = t & 63;
  const size_t idx = ((size_t)b * S_ + s) * 1024 + t;
  const float lf = (float)localb[idx], rf = (float)remote[idx];
  float part = lf * glw[d] + rf * grw[d];
#pragma unroll
  for (int off = 32; off; off >>= 1) part += __shfl_xor(part, off);
  const float g = 1.f / (1.f + __expf(-part));
  mixed[idx] = (bf16)(g * lf + (1.f - g) * rf);
}

// ---------------- launch ----------------
extern "C" void kernel_launch(void* const* d_in, const int* in_sizes, int n_in,
                              void* d_out, int out_size, void* d_ws, size_t ws_size,
                              hipStream_t stream)
{
  const float* x      = (const float*)d_in[0];
  const float* qkv_w  = (const float*)d_in[1];
  const float* qkv_b  = (const float*)d_in[2];
  const float* rq_w   = (const float*)d_in[3];
  const float* rq_b   = (const float*)d_in[4];
  const float* rkv_w  = (const float*)d_in[5];
  const float* rkv_b  = (const float*)d_in[6];
  const float* rout_w = (const float*)d_in[7];
  const float* rout_b = (const float*)d_in[8];
  const float* out_w  = (const float*)d_in[9];
  const float* out_b  = (const float*)d_in[10];
  const float* gl_w   = (const float*)d_in[11];
  const float* gr_w   = (const float*)d_in[12];

  char* w = (char*)d_ws;
  bf16* qkvr_wt = (bf16*)w; w += (size_t)QSTR * 1024 * 2;
  bf16* rkv_wt  = (bf16*)w; w += (size_t)512 * 1024 * 2;
  bf16* rout_wt = (bf16*)w; w += (size_t)1024 * 256 * 2;
  bf16* out_wt  = (bf16*)w; w += (size_t)1024 * 1024 * 2;
  float* qkvr_b = (float*)w; w += (size_t)QSTR * 4;
  bf16* xb      = (bf16*)w; w += (size_t)B_ * S_ * 1024 * 2;
  bf16* qkvrb   = (bf16*)w; w += (size_t)B_ * S_ * QSTR * 2;
  bf16* rkvb    = (bf16*)w; w += (size_t)B_ * 64 * 512 * 2;
  bf16* latout  = (bf16*)w; w += (size_t)B_ * S_ * 256 * 2;
  bf16* remote  = (bf16*)w; w += (size_t)B_ * S_ * 1024 * 2;
  bf16* localb  = (bf16*)w; w += (size_t)B_ * S_ * 1024 * 2;
  bf16* mixed   = qkvrb;  // reuse: qkvrb dead after local_attn + latent

  hipMemcpyAsync(qkvr_b, qkv_b, 3072 * sizeof(float), hipMemcpyDeviceToDevice, stream);
  hipMemcpyAsync(qkvr_b + 3072, rq_b, 256 * sizeof(float), hipMemcpyDeviceToDevice, stream);

  prep_kernel<<<dim3(7168), 256, 0, stream>>>(qkv_w, rq_w, rkv_w, rout_w, out_w, x,
                                              qkvr_wt, rkv_wt, rout_wt, out_wt, xb);

  gemm8_kernel<bf16><<<dim3(32, 13), 512, 0, stream>>>(xb, qkvr_wt, qkvr_b, qkvrb, B_ * S_, QSTR, 1024);
  pool_rkv_kernel<<<dim3(128, 2), 256, 0, stream>>>(xb, rkv_wt, rkv_b, rkvb);
  latent_attn_kernel<<<dim3(B_ * S_), 256, 0, stream>>>(qkvrb, rkvb, latout);
  gemm_bias_kernel<bf16><<<dim3(64, 8), 256, 0, stream>>>(latout, rout_wt, rout_b, remote, B_ * S_, 1024, 256);
  local_attn_mfma<<<dim3(S_ / 128, 16, B_), 256, 0, stream>>>(qkvrb, localb);
  gate_mix_kernel<<<dim3(B_ * S_), 1024, 0, stream>>>(localb, remote, gl_w, gr_w, mixed);
  gemm_bias_kernel<float><<<dim3(64, 8), 256, 0, stream>>>(mixed, out_wt, out_b, (float*)d_out, B_ * S_, 1024, 1024);
}